// Round 1
// baseline (1272.277 us; speedup 1.0000x reference)
//
#include <hip/hip_runtime.h>

#define EPS 1e-5f

// ============================ GEMM =========================================
// C[M,Ncols] = relu?( A[M,Kdim] @ W[Kdim,Ncols] + bias + resid )
// Tile: 64 rows x 128 cols, K staged in chunks of 64.
// LDS: As 16KB + Ws 32KB = 48KB -> 3 blocks/CU (12 waves/CU).
__global__ __launch_bounds__(256) void gemm_k(
    const float* __restrict__ A, const float* __restrict__ W,
    const float* __restrict__ bias, const float* __restrict__ resid,
    float* __restrict__ C, int M, int Kdim, int Ncols, int relu)
{
    __shared__ float As[64 * 64];
    __shared__ float Ws[64 * 128];
    const int tid = threadIdx.x;
    const int tx = tid & 31;        // col quad: cols colBase + tx*4 .. +3
    const int ty = tid >> 5;        // rows rowBase + ty*8 .. +7
    const int rowBase = blockIdx.x * 64;
    const int colBase = blockIdx.y * 128;

    float4 acc[8];
#pragma unroll
    for (int i = 0; i < 8; ++i) acc[i] = make_float4(0.f, 0.f, 0.f, 0.f);

    const int nChunks = Kdim >> 6;
    for (int kc = 0; kc < nChunks; ++kc) {
        // stage A tile 64x64
#pragma unroll
        for (int j = 0; j < 4; ++j) {
            int idx = tid + j * 256;          // 0..1023 float4 slots
            int row = idx >> 4, c4 = idx & 15;
            int grow = rowBase + row;
            float4 v = make_float4(0.f, 0.f, 0.f, 0.f);
            if (grow < M)
                v = *(const float4*)&A[(size_t)grow * Kdim + kc * 64 + c4 * 4];
            ((float4*)As)[idx] = v;
        }
        // stage W tile 64x128
#pragma unroll
        for (int j = 0; j < 8; ++j) {
            int idx = tid + j * 256;          // 0..2047 float4 slots
            int row = idx >> 5, c4 = idx & 31;
            ((float4*)Ws)[idx] =
                *(const float4*)&W[(size_t)(kc * 64 + row) * Ncols + colBase + c4 * 4];
        }
        __syncthreads();
#pragma unroll 2
        for (int k4 = 0; k4 < 16; ++k4) {
            float4 w0 = ((float4*)Ws)[(k4 * 4 + 0) * 32 + tx];
            float4 w1 = ((float4*)Ws)[(k4 * 4 + 1) * 32 + tx];
            float4 w2 = ((float4*)Ws)[(k4 * 4 + 2) * 32 + tx];
            float4 w3 = ((float4*)Ws)[(k4 * 4 + 3) * 32 + tx];
#pragma unroll
            for (int i = 0; i < 8; ++i) {
                float4 a = ((float4*)As)[(ty * 8 + i) * 16 + k4];
                acc[i].x += a.x * w0.x + a.y * w1.x + a.z * w2.x + a.w * w3.x;
                acc[i].y += a.x * w0.y + a.y * w1.y + a.z * w2.y + a.w * w3.y;
                acc[i].z += a.x * w0.z + a.y * w1.z + a.z * w2.z + a.w * w3.z;
                acc[i].w += a.x * w0.w + a.y * w1.w + a.z * w2.w + a.w * w3.w;
            }
        }
        __syncthreads();
    }

    float4 b4 = make_float4(0.f, 0.f, 0.f, 0.f);
    if (bias) b4 = *(const float4*)&bias[colBase + tx * 4];
#pragma unroll
    for (int i = 0; i < 8; ++i) {
        int grow = rowBase + ty * 8 + i;
        if (grow >= M) continue;
        float4 r = acc[i];
        r.x += b4.x; r.y += b4.y; r.z += b4.z; r.w += b4.w;
        if (resid) {
            float4 h4 = *(const float4*)&resid[(size_t)grow * Ncols + colBase + tx * 4];
            r.x += h4.x; r.y += h4.y; r.z += h4.z; r.w += h4.w;
        }
        if (relu) {
            r.x = fmaxf(r.x, 0.f); r.y = fmaxf(r.y, 0.f);
            r.z = fmaxf(r.z, 0.f); r.w = fmaxf(r.w, 0.f);
        }
        *(float4*)&C[(size_t)grow * Ncols + colBase + tx * 4] = r;
    }
}

// ============================ CSR build ====================================
__global__ void hist_k(const int* __restrict__ dst, int E, int* __restrict__ cnt)
{
    for (int i = blockIdx.x * blockDim.x + threadIdx.x; i < E;
         i += gridDim.x * blockDim.x)
        atomicAdd(&cnt[dst[i]], 1);
}

// single-block exclusive scan over N counts -> row_ptr[N+1]
__global__ __launch_bounds__(1024) void scan_k(const int* __restrict__ cnt, int Nn,
                                               int* __restrict__ row_ptr)
{
    __shared__ int ts[1024];
    const int t = threadIdx.x;
    const int chunk = (Nn + 1023) >> 10;
    const int lo = t * chunk;
    const int hi = min(lo + chunk, Nn);
    int s = 0;
    for (int i = lo; i < hi; ++i) s += cnt[i];
    ts[t] = s;
    __syncthreads();
    for (int off = 1; off < 1024; off <<= 1) {
        int v = (t >= off) ? ts[t - off] : 0;
        __syncthreads();
        ts[t] += v;
        __syncthreads();
    }
    int run = (t > 0) ? ts[t - 1] : 0;
    for (int i = lo; i < hi; ++i) { row_ptr[i] = run; run += cnt[i]; }
    if (t == 1023) row_ptr[Nn] = ts[1023];
}

__global__ void scatter_k(const int* __restrict__ src, const int* __restrict__ dst,
                          int E, int* __restrict__ cursor, int* __restrict__ esrc)
{
    for (int i = blockIdx.x * blockDim.x + threadIdx.x; i < E;
         i += gridDim.x * blockDim.x) {
        int p = atomicAdd(&cursor[dst[i]], 1);
        esrc[p] = src[i];
    }
}

// ============================ edge attention ===============================
// One wave per dst node. 64 lanes = 8 heads x 8 lanes x 2 dims.
__global__ __launch_bounds__(256) void edge_attn_k(
    const float* __restrict__ Q, const float* __restrict__ K,
    const float* __restrict__ V, const int* __restrict__ row_ptr,
    const int* __restrict__ esrc, float* __restrict__ attn, int Nn)
{
    const int wave = threadIdx.x >> 6;
    const int lane = threadIdx.x & 63;
    const int node = blockIdx.x * 4 + wave;
    if (node >= Nn) return;
    const int off = (lane >> 3) * 16 + (lane & 7) * 2;  // head*16 + sub*2
    const float2 q = *(const float2*)&Q[node * 128 + off];
    const int e0 = row_ptr[node], e1 = row_ptr[node + 1];
    float wv0 = 0.f, wv1 = 0.f, z = 0.f;
    for (int e = e0; e < e1; ++e) {
        const int s = esrc[e];
        const float2 k2 = *(const float2*)&K[s * 128 + off];
        float p = k2.x * q.x + k2.y * q.y;
        p += __shfl_xor(p, 1);
        p += __shfl_xor(p, 2);
        p += __shfl_xor(p, 4);
        const float sc = __expf(fminf(fmaxf(p * 0.25f, -5.f), 5.f));
        const float2 v2 = *(const float2*)&V[s * 128 + off];
        wv0 += sc * v2.x;
        wv1 += sc * v2.y;
        z += sc;
    }
    const float inv = 1.f / z;
    *(float2*)&attn[node * 128 + off] = make_float2(wv0 * inv, wv1 * inv);
}

// ============================ BatchNorm ====================================
__global__ __launch_bounds__(256) void bn_stats_k(const float* __restrict__ X,
                                                  int Nrows, float* __restrict__ stats)
{
    const int col = threadIdx.x & 127;
    const int sub = threadIdx.x >> 7;  // 0/1
    float s = 0.f, ss = 0.f;
    for (int r = blockIdx.x * 2 + sub; r < Nrows; r += gridDim.x * 2) {
        float v = X[(size_t)r * 128 + col];
        s += v;
        ss += v * v;
    }
    __shared__ float ls[256], lss[256];
    ls[threadIdx.x] = s;
    lss[threadIdx.x] = ss;
    __syncthreads();
    if (threadIdx.x < 128) {
        atomicAdd(&stats[col], ls[col] + ls[col + 128]);
        atomicAdd(&stats[128 + col], lss[col] + lss[col + 128]);
    }
}

__global__ void bn_finalize_k(float* __restrict__ stats, const float* __restrict__ gamma,
                              const float* __restrict__ beta, int Nrows)
{
    const int c = threadIdx.x;  // 128 threads
    const float invN = 1.f / (float)Nrows;
    const float mu = stats[c] * invN;
    const float var = stats[128 + c] * invN - mu * mu;
    const float isg = rsqrtf(var + EPS) * gamma[c];
    stats[c] = isg;
    stats[128 + c] = beta[c] - mu * isg;
}

__global__ __launch_bounds__(256) void bn_apply_k(const float* __restrict__ X,
                                                  const float* __restrict__ stats,
                                                  int total4, float* __restrict__ out)
{
    for (int i = blockIdx.x * blockDim.x + threadIdx.x; i < total4;
         i += gridDim.x * blockDim.x) {
        const int c4 = i & 31;
        const float4 sc = ((const float4*)stats)[c4];
        const float4 sh = ((const float4*)stats)[32 + c4];
        float4 v = ((const float4*)X)[i];
        v.x = v.x * sc.x + sh.x;
        v.y = v.y * sc.y + sh.y;
        v.z = v.z * sc.z + sh.z;
        v.w = v.w * sc.w + sh.w;
        ((float4*)out)[i] = v;
    }
}

// ============================ launch =======================================
extern "C" void kernel_launch(void* const* d_in, const int* in_sizes, int n_in,
                              void* d_out, int out_size, void* d_ws, size_t ws_size,
                              hipStream_t stream)
{
    const float* h   = (const float*)d_in[0];
    const float* Wq  = (const float*)d_in[1];
    const float* Wk  = (const float*)d_in[2];
    const float* Wv  = (const float*)d_in[3];
    const float* Wo  = (const float*)d_in[4];
    const float* bo  = (const float*)d_in[5];
    const float* g1  = (const float*)d_in[6];
    const float* b1  = (const float*)d_in[7];
    const float* Wf1 = (const float*)d_in[8];
    const float* bf1 = (const float*)d_in[9];
    const float* Wf2 = (const float*)d_in[10];
    const float* bf2 = (const float*)d_in[11];
    const float* g2  = (const float*)d_in[12];
    const float* b2  = (const float*)d_in[13];
    const int*   src = (const int*)d_in[14];
    const int*   dstv= (const int*)d_in[15];
    const int N = in_sizes[0] / 128;
    const int E = in_sizes[14];

    float* out = (float*)d_out;                 // attn buffer, later final out
    float* Q     = (float*)d_ws;
    float* Km    = Q  + (size_t)N * 128;
    float* Vm    = Km + (size_t)N * 128;
    float* stats = Vm + (size_t)N * 128;        // 256 floats
    int* row_ptr = (int*)(stats + 256);         // N+1
    int* cnt     = row_ptr + (N + 1);           // N (counts, then cursor)
    int* esrc    = cnt + N;                     // E
    float* x      = Q;                          // reuse after QKV dead
    float* hidden = Km;                         // N*256 spans Km+Vm

    const dim3 b256(256);
    const int gm = (N + 63) / 64;

    // ---- CSR build (dst-bucketed edges) ----
    hipMemsetAsync(cnt, 0, (size_t)N * 4, stream);
    hist_k<<<dim3(2048), b256, 0, stream>>>(dstv, E, cnt);
    scan_k<<<dim3(1), dim3(1024), 0, stream>>>(cnt, N, row_ptr);
    hipMemcpyAsync(cnt, row_ptr, (size_t)N * 4, hipMemcpyDeviceToDevice, stream);
    scatter_k<<<dim3(2048), b256, 0, stream>>>(src, dstv, E, cnt, esrc);

    // ---- QKV projections ----
    gemm_k<<<dim3(gm, 1), b256, 0, stream>>>(h, Wq, nullptr, nullptr, Q,  N, 128, 128, 0);
    gemm_k<<<dim3(gm, 1), b256, 0, stream>>>(h, Wk, nullptr, nullptr, Km, N, 128, 128, 0);
    gemm_k<<<dim3(gm, 1), b256, 0, stream>>>(h, Wv, nullptr, nullptr, Vm, N, 128, 128, 0);

    // ---- sparse attention -> out holds attn ----
    edge_attn_k<<<dim3((N + 3) / 4), b256, 0, stream>>>(Q, Km, Vm, row_ptr, esrc, out, N);

    // ---- x = h + attn @ Wo + bo ----
    gemm_k<<<dim3(gm, 1), b256, 0, stream>>>(out, Wo, bo, h, x, N, 128, 128, 0);

    // ---- BN1 (in-place on x) ----
    hipMemsetAsync(stats, 0, 256 * 4, stream);
    bn_stats_k<<<dim3(512), b256, 0, stream>>>(x, N, stats);
    bn_finalize_k<<<dim3(1), dim3(128), 0, stream>>>(stats, g1, b1, N);
    bn_apply_k<<<dim3(1024), b256, 0, stream>>>(x, stats, N * 32, x);

    // ---- FFN ----
    gemm_k<<<dim3(gm, 2), b256, 0, stream>>>(x, Wf1, bf1, nullptr, hidden, N, 128, 256, 1);
    gemm_k<<<dim3(gm, 1), b256, 0, stream>>>(hidden, Wf2, bf2, x, out, N, 256, 128, 0);

    // ---- BN2 (in-place on out) ----
    hipMemsetAsync(stats, 0, 256 * 4, stream);
    bn_stats_k<<<dim3(512), b256, 0, stream>>>(out, N, stats);
    bn_finalize_k<<<dim3(1), dim3(128), 0, stream>>>(stats, g2, b2, N);
    bn_apply_k<<<dim3(1024), b256, 0, stream>>>(out, stats, N * 32, out);
}

// Round 2
// 1013.229 us; speedup vs baseline: 1.2557x; 1.2557x over previous
//
#include <hip/hip_runtime.h>

#define EPS 1e-5f

typedef __attribute__((ext_vector_type(8))) short sh8;
typedef __attribute__((ext_vector_type(4))) float f4;

static __device__ __forceinline__ unsigned short f2b(float f) {
    union { float f; unsigned u; } v; v.f = f;
    unsigned r = v.u + 0x7FFF + ((v.u >> 16) & 1);  // RNE
    return (unsigned short)(r >> 16);
}
static __device__ __forceinline__ float b2f(unsigned short b) {
    union { unsigned u; float f; } v; v.u = ((unsigned)b) << 16; return v.f;
}

// ===================== weight prep: fp32 [K][N] -> bf16 [N][K] =============
__global__ __launch_bounds__(256) void prep_w_k(const float* __restrict__ W,
                                                unsigned short* __restrict__ Wt,
                                                int K, int Nc)
{
    int i = blockIdx.x * 256 + threadIdx.x;
    if (i >= K * Nc) return;
    int k = i / Nc, n = i - k * Nc;       // coalesced read of W
    Wt[(size_t)n * K + k] = f2b(W[i]);
}

// ===================== MFMA GEMM ===========================================
// C[M,*] = act( A[M,Kdim] @ W + bias + resid ), W given pre-transposed bf16
// [n][k]. Tile 128x128, BK=64, 4 waves each computing a 64x64 quadrant via
// 4x4 grid of 16x16x32 bf16 MFMA. LDS 2*128*72*2B = 36KB -> 4 blocks/CU.
// OMODE: 0 = fp32 out, 1 = bf16 out, 2 = bf16 KV-interleaved out (slot 0=K,2=V)
template<int ABF16, int OMODE>
__global__ __launch_bounds__(256) void mm_k(
    const void* __restrict__ Ap, const unsigned short* __restrict__ Wt,
    const float* __restrict__ bias, const float* __restrict__ resid,
    void* __restrict__ Cp, int M, int Kdim, int ldc, int relu, int slot)
{
    __shared__ __align__(16) unsigned short As[128 * 72];
    __shared__ __align__(16) unsigned short Ws[128 * 72];
    const int tid = threadIdx.x;
    const int wave = tid >> 6, lane = tid & 63;
    const int q = lane >> 4, lm = lane & 15;
    const int rowBase = blockIdx.x * 128;
    const int colBase = blockIdx.y * 128;
    const unsigned short* Wblk = Wt + (size_t)colBase * Kdim;
    const int r0 = (wave & 1) * 64, c0 = (wave >> 1) * 64;

    f4 acc[4][4];
#pragma unroll
    for (int mi = 0; mi < 4; ++mi)
#pragma unroll
        for (int ni = 0; ni < 4; ++ni) {
            f4 z = {0.f, 0.f, 0.f, 0.f};
            acc[mi][ni] = z;
        }

    for (int kc = 0; kc < Kdim; kc += 64) {
        if (ABF16) {
            const unsigned short* A = (const unsigned short*)Ap;
#pragma unroll
            for (int j = 0; j < 4; ++j) {
                int idx = tid + j * 256;          // 1024 uint4 slots
                int row = idx >> 3, kk = (idx & 7) * 8;
                int grow = rowBase + row;
                uint4 v = make_uint4(0u, 0u, 0u, 0u);
                if (grow < M) v = *(const uint4*)&A[(size_t)grow * Kdim + kc + kk];
                *(uint4*)&As[row * 72 + kk] = v;
            }
        } else {
            const float* A = (const float*)Ap;
#pragma unroll
            for (int j = 0; j < 8; ++j) {
                int idx = tid + j * 256;          // 2048 float4 slots
                int row = idx >> 4, kk = (idx & 15) * 4;
                int grow = rowBase + row;
                float4 v = make_float4(0.f, 0.f, 0.f, 0.f);
                if (grow < M) v = *(const float4*)&A[(size_t)grow * Kdim + kc + kk];
                ushort4 b;
                b.x = f2b(v.x); b.y = f2b(v.y); b.z = f2b(v.z); b.w = f2b(v.w);
                *(ushort4*)&As[row * 72 + kk] = b;
            }
        }
#pragma unroll
        for (int j = 0; j < 4; ++j) {
            int idx = tid + j * 256;
            int n = idx >> 3, kk = (idx & 7) * 8;
            uint4 v = *(const uint4*)&Wblk[(size_t)n * Kdim + kc + kk];
            *(uint4*)&Ws[n * 72 + kk] = v;
        }
        __syncthreads();
#pragma unroll
        for (int k2 = 0; k2 < 2; ++k2) {
            sh8 af[4], bfr[4];
#pragma unroll
            for (int t = 0; t < 4; ++t) {
                af[t]  = *(const sh8*)&As[(r0 + t * 16 + lm) * 72 + k2 * 32 + q * 8];
                bfr[t] = *(const sh8*)&Ws[(c0 + t * 16 + lm) * 72 + k2 * 32 + q * 8];
            }
#pragma unroll
            for (int mi = 0; mi < 4; ++mi)
#pragma unroll
                for (int ni = 0; ni < 4; ++ni)
                    acc[mi][ni] = __builtin_amdgcn_mfma_f32_16x16x32_bf16(
                        af[mi], bfr[ni], acc[mi][ni], 0, 0, 0);
        }
        __syncthreads();
    }

#pragma unroll
    for (int mi = 0; mi < 4; ++mi) {
#pragma unroll
        for (int ni = 0; ni < 4; ++ni) {
            const int col = c0 + ni * 16 + lm;
            const int gcol = colBase + col;
            const float bv = bias ? bias[gcol] : 0.f;
#pragma unroll
            for (int r = 0; r < 4; ++r) {
                int grow = rowBase + r0 + mi * 16 + q * 4 + r;
                if (grow >= M) continue;
                float val = acc[mi][ni][r] + bv;
                if (resid) val += resid[(size_t)grow * ldc + gcol];
                if (relu) val = fmaxf(val, 0.f);
                if (OMODE == 0)
                    ((float*)Cp)[(size_t)grow * ldc + gcol] = val;
                else if (OMODE == 1)
                    ((unsigned short*)Cp)[(size_t)grow * ldc + gcol] = f2b(val);
                else
                    ((unsigned short*)Cp)[(size_t)grow * 256 + ((gcol >> 1) << 2) +
                                          (gcol & 1) + slot] = f2b(val);
            }
        }
    }
}

// ============================ CSR build ====================================
__global__ void hist_k(const int* __restrict__ dst, int E, int* __restrict__ cnt)
{
    for (int i = blockIdx.x * blockDim.x + threadIdx.x; i < E;
         i += gridDim.x * blockDim.x)
        atomicAdd(&cnt[dst[i]], 1);
}

__global__ __launch_bounds__(1024) void scan_k(const int* __restrict__ cnt, int Nn,
                                               int* __restrict__ row_ptr)
{
    __shared__ int ts[1024];
    const int t = threadIdx.x;
    const int chunk = (Nn + 1023) >> 10;
    const int lo = t * chunk;
    const int hi = min(lo + chunk, Nn);
    int s = 0;
    for (int i = lo; i < hi; ++i) s += cnt[i];
    ts[t] = s;
    __syncthreads();
    for (int off = 1; off < 1024; off <<= 1) {
        int v = (t >= off) ? ts[t - off] : 0;
        __syncthreads();
        ts[t] += v;
        __syncthreads();
    }
    int run = (t > 0) ? ts[t - 1] : 0;
    for (int i = lo; i < hi; ++i) { row_ptr[i] = run; run += cnt[i]; }
    if (t == 1023) row_ptr[Nn] = ts[1023];
}

__global__ void scatter_k(const int* __restrict__ src, const int* __restrict__ dst,
                          int E, int* __restrict__ cursor, int* __restrict__ esrc)
{
    for (int i = blockIdx.x * blockDim.x + threadIdx.x; i < E;
         i += gridDim.x * blockDim.x) {
        int p = atomicAdd(&cursor[dst[i]], 1);
        esrc[p] = src[i];
    }
}

// ============================ edge attention ===============================
// One wave per dst node. Lane l owns head (l>>3), dims (2l, 2l+1).
// KVp row (512B/node): pair p -> [K2p, K2p+1, V2p, V2p+1] bf16.
__global__ __launch_bounds__(256) void edge_attn_k(
    const unsigned short* __restrict__ Qb, const unsigned short* __restrict__ KVp,
    const int* __restrict__ row_ptr, const int* __restrict__ esrc,
    unsigned short* __restrict__ attnb, int Nn)
{
    const int wave = threadIdx.x >> 6, lane = threadIdx.x & 63;
    const int node = blockIdx.x * 4 + wave;
    if (node >= Nn) return;
    const unsigned qp = *(const unsigned*)&Qb[node * 128 + lane * 2];
    const float qx = b2f((unsigned short)(qp & 0xffff));
    const float qy = b2f((unsigned short)(qp >> 16));
    const int e0 = row_ptr[node], e1 = row_ptr[node + 1];
    const int cnt = e1 - e0;
    int myS = (lane < cnt) ? esrc[e0 + lane] : 0;
    float wv0 = 0.f, wv1 = 0.f, z = 0.f;
    const int n1 = min(cnt, 64);
    int j = 0;
    for (; j + 1 < n1; j += 2) {
        const int s0 = __shfl(myS, j);
        const int s1 = __shfl(myS, j + 1);
        const uint2 kv0 = *(const uint2*)&KVp[(size_t)s0 * 256 + lane * 4];
        const uint2 kv1 = *(const uint2*)&KVp[(size_t)s1 * 256 + lane * 4];
        {
            float p = b2f((unsigned short)(kv0.x & 0xffff)) * qx +
                      b2f((unsigned short)(kv0.x >> 16)) * qy;
            p += __shfl_xor(p, 1); p += __shfl_xor(p, 2); p += __shfl_xor(p, 4);
            const float sc = __expf(fminf(fmaxf(p * 0.25f, -5.f), 5.f));
            wv0 += sc * b2f((unsigned short)(kv0.y & 0xffff));
            wv1 += sc * b2f((unsigned short)(kv0.y >> 16));
            z += sc;
        }
        {
            float p = b2f((unsigned short)(kv1.x & 0xffff)) * qx +
                      b2f((unsigned short)(kv1.x >> 16)) * qy;
            p += __shfl_xor(p, 1); p += __shfl_xor(p, 2); p += __shfl_xor(p, 4);
            const float sc = __expf(fminf(fmaxf(p * 0.25f, -5.f), 5.f));
            wv0 += sc * b2f((unsigned short)(kv1.y & 0xffff));
            wv1 += sc * b2f((unsigned short)(kv1.y >> 16));
            z += sc;
        }
    }
    for (; j < n1; ++j) {
        const int s0 = __shfl(myS, j);
        const uint2 kv0 = *(const uint2*)&KVp[(size_t)s0 * 256 + lane * 4];
        float p = b2f((unsigned short)(kv0.x & 0xffff)) * qx +
                  b2f((unsigned short)(kv0.x >> 16)) * qy;
        p += __shfl_xor(p, 1); p += __shfl_xor(p, 2); p += __shfl_xor(p, 4);
        const float sc = __expf(fminf(fmaxf(p * 0.25f, -5.f), 5.f));
        wv0 += sc * b2f((unsigned short)(kv0.y & 0xffff));
        wv1 += sc * b2f((unsigned short)(kv0.y >> 16));
        z += sc;
    }
    for (int e = e0 + 64; e < e1; ++e) {    // rare: deg > 64
        const int s0 = esrc[e];
        const uint2 kv0 = *(const uint2*)&KVp[(size_t)s0 * 256 + lane * 4];
        float p = b2f((unsigned short)(kv0.x & 0xffff)) * qx +
                  b2f((unsigned short)(kv0.x >> 16)) * qy;
        p += __shfl_xor(p, 1); p += __shfl_xor(p, 2); p += __shfl_xor(p, 4);
        const float sc = __expf(fminf(fmaxf(p * 0.25f, -5.f), 5.f));
        wv0 += sc * b2f((unsigned short)(kv0.y & 0xffff));
        wv1 += sc * b2f((unsigned short)(kv0.y >> 16));
        z += sc;
    }
    const float inv = 1.f / z;
    const unsigned outp = (unsigned)f2b(wv0 * inv) | ((unsigned)f2b(wv1 * inv) << 16);
    *(unsigned*)&attnb[node * 128 + lane * 2] = outp;
}

// ============================ BatchNorm ====================================
__global__ __launch_bounds__(256) void bn_stats_k(const float* __restrict__ X,
                                                  int Nrows, float* __restrict__ stats)
{
    const int col = threadIdx.x & 127;
    const int sub = threadIdx.x >> 7;
    float s = 0.f, ss = 0.f;
    for (int r = blockIdx.x * 2 + sub; r < Nrows; r += gridDim.x * 2) {
        float v = X[(size_t)r * 128 + col];
        s += v; ss += v * v;
    }
    __shared__ float ls[256], lss[256];
    ls[threadIdx.x] = s; lss[threadIdx.x] = ss;
    __syncthreads();
    if (threadIdx.x < 128) {
        atomicAdd(&stats[col], ls[col] + ls[col + 128]);
        atomicAdd(&stats[128 + col], lss[col] + lss[col + 128]);
    }
}

__global__ void bn_finalize_k(float* __restrict__ stats, const float* __restrict__ gamma,
                              const float* __restrict__ beta, int Nrows)
{
    const int c = threadIdx.x;  // 128 threads
    const float invN = 1.f / (float)Nrows;
    const float mu = stats[c] * invN;
    const float var = stats[128 + c] * invN - mu * mu;
    const float isg = rsqrtf(var + EPS) * gamma[c];
    stats[c] = isg;
    stats[128 + c] = beta[c] - mu * isg;
}

__global__ __launch_bounds__(256) void bn_apply_k(const float* __restrict__ X,
                                                  const float* __restrict__ stats,
                                                  int total4, float* __restrict__ out)
{
    for (int i = blockIdx.x * blockDim.x + threadIdx.x; i < total4;
         i += gridDim.x * blockDim.x) {
        const int c4 = i & 31;
        const float4 sc = ((const float4*)stats)[c4];
        const float4 sh = ((const float4*)stats)[32 + c4];
        float4 v = ((const float4*)X)[i];
        v.x = v.x * sc.x + sh.x;
        v.y = v.y * sc.y + sh.y;
        v.z = v.z * sc.z + sh.z;
        v.w = v.w * sc.w + sh.w;
        ((float4*)out)[i] = v;
    }
}

// ============================ launch =======================================
extern "C" void kernel_launch(void* const* d_in, const int* in_sizes, int n_in,
                              void* d_out, int out_size, void* d_ws, size_t ws_size,
                              hipStream_t stream)
{
    const float* h   = (const float*)d_in[0];
    const float* Wq  = (const float*)d_in[1];
    const float* Wk  = (const float*)d_in[2];
    const float* Wv  = (const float*)d_in[3];
    const float* Wo  = (const float*)d_in[4];
    const float* bo  = (const float*)d_in[5];
    const float* g1  = (const float*)d_in[6];
    const float* b1  = (const float*)d_in[7];
    const float* Wf1 = (const float*)d_in[8];
    const float* bf1 = (const float*)d_in[9];
    const float* Wf2 = (const float*)d_in[10];
    const float* bf2 = (const float*)d_in[11];
    const float* g2  = (const float*)d_in[12];
    const float* b2  = (const float*)d_in[13];
    const int*   src = (const int*)d_in[14];
    const int*   dstv= (const int*)d_in[15];
    const int N = in_sizes[0] / 128;
    const int E = in_sizes[14];

    // ---- workspace layout ----
    unsigned short* Wt   = (unsigned short*)d_ws;            // 131072 bf16
    float* stats         = (float*)((char*)d_ws + 262144);   // 256 f
    unsigned short* Qb   = (unsigned short*)((char*)d_ws + 263168);  // N*128 bf16
    unsigned short* attnb= Qb + (size_t)N * 128;             // N*128 bf16
    unsigned short* KVp  = attnb + (size_t)N * 128;          // N*256 bf16
    int* esrc    = (int*)(KVp + (size_t)N * 256);            // E
    int* cnt     = esrc + E;                                 // N
    int* row_ptr = cnt + N;                                  // N+1
    unsigned short* hidden = Qb;        // N*256 bf16, overlays Qb+attnb (dead)
    float* x = (float*)KVp;             // N*128 fp32, overlays KVp (dead)

    unsigned short* WqT  = Wt;
    unsigned short* WkT  = Wt + 16384;
    unsigned short* WvT  = Wt + 32768;
    unsigned short* WoT  = Wt + 49152;
    unsigned short* Wf1T = Wt + 65536;  // [256][128]
    unsigned short* Wf2T = Wt + 98304;  // [128][256]

    float* out = (float*)d_out;
    const dim3 b256(256);
    const int gm = (N + 127) / 128;

    // ---- weight prep ----
    prep_w_k<<<dim3(64),  b256, 0, stream>>>(Wq,  WqT,  128, 128);
    prep_w_k<<<dim3(64),  b256, 0, stream>>>(Wk,  WkT,  128, 128);
    prep_w_k<<<dim3(64),  b256, 0, stream>>>(Wv,  WvT,  128, 128);
    prep_w_k<<<dim3(64),  b256, 0, stream>>>(Wo,  WoT,  128, 128);
    prep_w_k<<<dim3(128), b256, 0, stream>>>(Wf1, Wf1T, 128, 256);
    prep_w_k<<<dim3(128), b256, 0, stream>>>(Wf2, Wf2T, 256, 128);

    // ---- CSR build ----
    hipMemsetAsync(cnt, 0, (size_t)N * 4, stream);
    hist_k<<<dim3(2048), b256, 0, stream>>>(dstv, E, cnt);
    scan_k<<<dim3(1), dim3(1024), 0, stream>>>(cnt, N, row_ptr);
    hipMemcpyAsync(cnt, row_ptr, (size_t)N * 4, hipMemcpyDeviceToDevice, stream);
    scatter_k<<<dim3(2048), b256, 0, stream>>>(src, dstv, E, cnt, esrc);

    // ---- QKV projections (fp32 in, bf16 out; K/V interleaved) ----
    mm_k<0,1><<<dim3(gm, 1), b256, 0, stream>>>(h, WqT, nullptr, nullptr, Qb,  N, 128, 128, 0, 0);
    mm_k<0,2><<<dim3(gm, 1), b256, 0, stream>>>(h, WkT, nullptr, nullptr, KVp, N, 128, 128, 0, 0);
    mm_k<0,2><<<dim3(gm, 1), b256, 0, stream>>>(h, WvT, nullptr, nullptr, KVp, N, 128, 128, 0, 2);

    // ---- sparse attention ----
    edge_attn_k<<<dim3((N + 3) / 4), b256, 0, stream>>>(Qb, KVp, row_ptr, esrc, attnb, N);

    // ---- x = h + attn @ Wo + bo (fp32 out, overlays KVp) ----
    mm_k<1,0><<<dim3(gm, 1), b256, 0, stream>>>(attnb, WoT, bo, h, x, N, 128, 128, 0, 0);

    // ---- BN1 in-place on x ----
    hipMemsetAsync(stats, 0, 256 * 4, stream);
    bn_stats_k<<<dim3(512), b256, 0, stream>>>(x, N, stats);
    bn_finalize_k<<<dim3(1), dim3(128), 0, stream>>>(stats, g1, b1, N);
    bn_apply_k<<<dim3(1024), b256, 0, stream>>>(x, stats, N * 32, x);

    // ---- FFN ----
    mm_k<0,1><<<dim3(gm, 2), b256, 0, stream>>>(x, Wf1T, bf1, nullptr, hidden, N, 128, 256, 1, 0);
    mm_k<1,0><<<dim3(gm, 1), b256, 0, stream>>>(hidden, Wf2T, bf2, x, out, N, 256, 128, 0, 0);

    // ---- BN2 in-place on out ----
    hipMemsetAsync(stats, 0, 256 * 4, stream);
    bn_stats_k<<<dim3(512), b256, 0, stream>>>(out, N, stats);
    bn_finalize_k<<<dim3(1), dim3(128), 0, stream>>>(stats, g2, b2, N);
    bn_apply_k<<<dim3(1024), b256, 0, stream>>>(out, stats, N * 32, out);
}

// Round 3
// 760.699 us; speedup vs baseline: 1.6725x; 1.3320x over previous
//
#include <hip/hip_runtime.h>

#define EPS 1e-5f

typedef __attribute__((ext_vector_type(8))) short sh8;
typedef __attribute__((ext_vector_type(4))) float f4;

static __device__ __forceinline__ unsigned short f2b(float f) {
    union { float f; unsigned u; } v; v.f = f;
    unsigned r = v.u + 0x7FFF + ((v.u >> 16) & 1);  // RNE
    return (unsigned short)(r >> 16);
}
static __device__ __forceinline__ float b2f(unsigned short b) {
    union { unsigned u; float f; } v; v.u = ((unsigned)b) << 16; return v.f;
}

// ===================== weight prep: fp32 [K][N] -> bf16 [N][K] =============
__global__ __launch_bounds__(256) void prep_w_k(const float* __restrict__ W,
                                                unsigned short* __restrict__ Wt,
                                                int K, int Nc)
{
    int i = blockIdx.x * 256 + threadIdx.x;
    if (i >= K * Nc) return;
    int k = i / Nc, n = i - k * Nc;
    Wt[(size_t)n * K + k] = f2b(W[i]);
}

// ===================== fused QKV GEMM ======================================
// A-tile (128 rows x full K=128) staged once as bf16; loop over 3 weights.
// LDS: As 128*136*2 = 34KB + Ws 128*72*2 = 18KB -> 52KB -> 3 blocks/CU.
__global__ __launch_bounds__(256) void qkv_k(
    const float* __restrict__ h, const unsigned short* __restrict__ Wt,
    unsigned short* __restrict__ Qb, unsigned short* __restrict__ KVp, int M)
{
    __shared__ __align__(16) unsigned short As[128 * 136];
    __shared__ __align__(16) unsigned short Ws[128 * 72];
    const int tid = threadIdx.x;
    const int wave = tid >> 6, lane = tid & 63;
    const int q = lane >> 4, lm = lane & 15;
    const int rowBase = blockIdx.x * 128;
    const int r0 = (wave & 1) * 64, c0 = (wave >> 1) * 64;

#pragma unroll
    for (int j = 0; j < 16; ++j) {
        int idx = tid + j * 256;             // 4096 float4 slots
        int row = idx >> 5, kk = (idx & 31) * 4;
        int grow = rowBase + row;
        float4 v = make_float4(0.f, 0.f, 0.f, 0.f);
        if (grow < M) v = *(const float4*)&h[(size_t)grow * 128 + kk];
        ushort4 b;
        b.x = f2b(v.x); b.y = f2b(v.y); b.z = f2b(v.z); b.w = f2b(v.w);
        *(ushort4*)&As[row * 136 + kk] = b;
    }

    for (int w = 0; w < 3; ++w) {
        f4 acc[4][4];
#pragma unroll
        for (int mi = 0; mi < 4; ++mi)
#pragma unroll
            for (int ni = 0; ni < 4; ++ni) {
                f4 z = {0.f, 0.f, 0.f, 0.f};
                acc[mi][ni] = z;
            }
        for (int kc = 0; kc < 2; ++kc) {
#pragma unroll
            for (int j = 0; j < 4; ++j) {
                int idx = tid + j * 256;      // 1024 uint4 slots
                int n = idx >> 3, kk = (idx & 7) * 8;
                uint4 v = *(const uint4*)&Wt[(size_t)w * 16384 + (size_t)n * 128 + kc * 64 + kk];
                *(uint4*)&Ws[n * 72 + kk] = v;
            }
            __syncthreads();
#pragma unroll
            for (int k2 = 0; k2 < 2; ++k2) {
                sh8 af[4], bfr[4];
#pragma unroll
                for (int t = 0; t < 4; ++t) {
                    af[t]  = *(const sh8*)&As[(r0 + t * 16 + lm) * 136 + kc * 64 + k2 * 32 + q * 8];
                    bfr[t] = *(const sh8*)&Ws[(c0 + t * 16 + lm) * 72 + k2 * 32 + q * 8];
                }
#pragma unroll
                for (int mi = 0; mi < 4; ++mi)
#pragma unroll
                    for (int ni = 0; ni < 4; ++ni)
                        acc[mi][ni] = __builtin_amdgcn_mfma_f32_16x16x32_bf16(
                            af[mi], bfr[ni], acc[mi][ni], 0, 0, 0);
            }
            __syncthreads();
        }
        const int slot = (w == 2) ? 2 : 0;
#pragma unroll
        for (int mi = 0; mi < 4; ++mi)
#pragma unroll
            for (int ni = 0; ni < 4; ++ni) {
                const int col = c0 + ni * 16 + lm;
#pragma unroll
                for (int r = 0; r < 4; ++r) {
                    int grow = rowBase + r0 + mi * 16 + q * 4 + r;
                    if (grow >= M) continue;
                    unsigned short b = f2b(acc[mi][ni][r]);
                    if (w == 0)
                        Qb[(size_t)grow * 128 + col] = b;
                    else
                        KVp[(size_t)grow * 256 + ((col >> 1) << 2) + (col & 1) + slot] = b;
                }
            }
    }
}

// ===================== MFMA GEMM ===========================================
// AMODE: 0 fp32 A, 1 bf16 A, 2 fp32 A with affine astats (BN apply on read)
// OMODE: 0 fp32 out, 1 bf16 out
// RESMODE: 0 none, 1 fp32 resid, 2 fp32 resid with affine sstats
// STATS: accumulate per-column sum/sumsq of output into ostats (atomics)
template<int AMODE, int OMODE, int RESMODE, int STATS>
__global__ __launch_bounds__(256) void mm_k(
    const void* __restrict__ Ap, const unsigned short* __restrict__ Wt,
    const float* __restrict__ bias, const float* __restrict__ resid,
    void* __restrict__ Cp, int M, int Kdim, int ldc, int relu,
    const float* __restrict__ astats, const float* __restrict__ sstats,
    float* __restrict__ ostats)
{
    __shared__ __align__(16) unsigned short As[128 * 72];
    __shared__ __align__(16) unsigned short Ws[128 * 72];
    const int tid = threadIdx.x;
    const int wave = tid >> 6, lane = tid & 63;
    const int q = lane >> 4, lm = lane & 15;
    const int rowBase = blockIdx.x * 128;
    const int colBase = blockIdx.y * 128;
    const unsigned short* Wblk = Wt + (size_t)colBase * Kdim;
    const int r0 = (wave & 1) * 64, c0 = (wave >> 1) * 64;

    f4 acc[4][4];
#pragma unroll
    for (int mi = 0; mi < 4; ++mi)
#pragma unroll
        for (int ni = 0; ni < 4; ++ni) {
            f4 z = {0.f, 0.f, 0.f, 0.f};
            acc[mi][ni] = z;
        }

    for (int kc = 0; kc < Kdim; kc += 64) {
        if (AMODE == 1) {
            const unsigned short* A = (const unsigned short*)Ap;
#pragma unroll
            for (int j = 0; j < 4; ++j) {
                int idx = tid + j * 256;
                int row = idx >> 3, kk = (idx & 7) * 8;
                int grow = rowBase + row;
                uint4 v = make_uint4(0u, 0u, 0u, 0u);
                if (grow < M) v = *(const uint4*)&A[(size_t)grow * Kdim + kc + kk];
                *(uint4*)&As[row * 72 + kk] = v;
            }
        } else {
            const float* A = (const float*)Ap;
#pragma unroll
            for (int j = 0; j < 8; ++j) {
                int idx = tid + j * 256;
                int row = idx >> 4, kk = (idx & 15) * 4;
                int grow = rowBase + row;
                float4 v = make_float4(0.f, 0.f, 0.f, 0.f);
                if (grow < M) v = *(const float4*)&A[(size_t)grow * Kdim + kc + kk];
                if (AMODE == 2) {
                    const int f = kc + kk;
                    const float4 sc = *(const float4*)&astats[f];
                    const float4 sh = *(const float4*)&astats[128 + f];
                    v.x = v.x * sc.x + sh.x; v.y = v.y * sc.y + sh.y;
                    v.z = v.z * sc.z + sh.z; v.w = v.w * sc.w + sh.w;
                }
                ushort4 b;
                b.x = f2b(v.x); b.y = f2b(v.y); b.z = f2b(v.z); b.w = f2b(v.w);
                *(ushort4*)&As[row * 72 + kk] = b;
            }
        }
#pragma unroll
        for (int j = 0; j < 4; ++j) {
            int idx = tid + j * 256;
            int n = idx >> 3, kk = (idx & 7) * 8;
            uint4 v = *(const uint4*)&Wblk[(size_t)n * Kdim + kc + kk];
            *(uint4*)&Ws[n * 72 + kk] = v;
        }
        __syncthreads();
#pragma unroll
        for (int k2 = 0; k2 < 2; ++k2) {
            sh8 af[4], bfr[4];
#pragma unroll
            for (int t = 0; t < 4; ++t) {
                af[t]  = *(const sh8*)&As[(r0 + t * 16 + lm) * 72 + k2 * 32 + q * 8];
                bfr[t] = *(const sh8*)&Ws[(c0 + t * 16 + lm) * 72 + k2 * 32 + q * 8];
            }
#pragma unroll
            for (int mi = 0; mi < 4; ++mi)
#pragma unroll
                for (int ni = 0; ni < 4; ++ni)
                    acc[mi][ni] = __builtin_amdgcn_mfma_f32_16x16x32_bf16(
                        af[mi], bfr[ni], acc[mi][ni], 0, 0, 0);
        }
        __syncthreads();
    }

#pragma unroll
    for (int ni = 0; ni < 4; ++ni) {
        const int gcol = colBase + c0 + ni * 16 + lm;
        const float bv = bias ? bias[gcol] : 0.f;
        float s = 0.f, ss = 0.f;
#pragma unroll
        for (int mi = 0; mi < 4; ++mi) {
#pragma unroll
            for (int r = 0; r < 4; ++r) {
                int grow = rowBase + r0 + mi * 16 + q * 4 + r;
                if (grow >= M) continue;
                float val = acc[mi][ni][r] + bv;
                if (RESMODE == 1) val += resid[(size_t)grow * ldc + gcol];
                if (RESMODE == 2) val += resid[(size_t)grow * ldc + gcol] * sstats[gcol] + sstats[128 + gcol];
                if (relu) val = fmaxf(val, 0.f);
                if (STATS) { s += val; ss += val * val; }
                if (OMODE == 0) ((float*)Cp)[(size_t)grow * ldc + gcol] = val;
                else ((unsigned short*)Cp)[(size_t)grow * ldc + gcol] = f2b(val);
            }
        }
        if (STATS) {
            s += __shfl_xor(s, 16); s += __shfl_xor(s, 32);
            ss += __shfl_xor(ss, 16); ss += __shfl_xor(ss, 32);
            if (q == 0) {
                atomicAdd(&ostats[gcol], s);
                atomicAdd(&ostats[128 + gcol], ss);
            }
        }
    }
}

// ============================ CSR build ====================================
__global__ void hist_k(const int* __restrict__ dst, int E, int* __restrict__ cnt)
{
    for (int i = blockIdx.x * blockDim.x + threadIdx.x; i < E;
         i += gridDim.x * blockDim.x)
        atomicAdd(&cnt[dst[i]], 1);
}

// Phase A: per-block (1024 elems) sums
__global__ __launch_bounds__(256) void part_sum_k(const int* __restrict__ cnt, int Nn,
                                                  int* __restrict__ blkSum)
{
    __shared__ int red[256];
    const int t = threadIdx.x;
    const int idx = blockIdx.x * 1024 + t * 4;
    int s = 0;
    if (idx + 4 <= Nn) {
        int4 v = *(const int4*)&cnt[idx];
        s = v.x + v.y + v.z + v.w;
    } else {
        for (int i = idx; i < Nn && i < idx + 4; ++i) s += cnt[i];
    }
    red[t] = s;
    __syncthreads();
    for (int off = 128; off > 0; off >>= 1) {
        if (t < off) red[t] += red[t + off];
        __syncthreads();
    }
    if (t == 0) blkSum[blockIdx.x] = red[0];
}

// Phase B: single-block scan of <=256 block sums; also writes row_ptr[Nn]
__global__ __launch_bounds__(256) void scan_blk_k(const int* __restrict__ blkSum, int NB,
                                                  int* __restrict__ blkOff,
                                                  int* __restrict__ row_ptr, int Nn)
{
    __shared__ int ts[256];
    const int t = threadIdx.x;
    const int v = (t < NB) ? blkSum[t] : 0;
    ts[t] = v;
    __syncthreads();
    for (int off = 1; off < 256; off <<= 1) {
        int u = (t >= off) ? ts[t - off] : 0;
        __syncthreads();
        ts[t] += u;
        __syncthreads();
    }
    if (t < NB) blkOff[t] = ts[t] - v;
    if (t == 255) row_ptr[Nn] = ts[255];
}

// Phase C: per-block local scan + global offset; writes row_ptr AND cursor
__global__ __launch_bounds__(256) void scan_write_k(int* __restrict__ cnt, int Nn,
                                                    const int* __restrict__ blkOff,
                                                    int* __restrict__ row_ptr)
{
    __shared__ int ts[256];
    const int t = threadIdx.x;
    const int idx = blockIdx.x * 1024 + t * 4;
    int4 v = make_int4(0, 0, 0, 0);
    if (idx + 4 <= Nn) v = *(const int4*)&cnt[idx];
    else {
        if (idx     < Nn) v.x = cnt[idx];
        if (idx + 1 < Nn) v.y = cnt[idx + 1];
        if (idx + 2 < Nn) v.z = cnt[idx + 2];
        if (idx + 3 < Nn) v.w = cnt[idx + 3];
    }
    const int s = v.x + v.y + v.z + v.w;
    ts[t] = s;
    __syncthreads();
    for (int off = 1; off < 256; off <<= 1) {
        int u = (t >= off) ? ts[t - off] : 0;
        __syncthreads();
        ts[t] += u;
        __syncthreads();
    }
    const int off0 = blkOff[blockIdx.x] + ts[t] - s;
    int4 o;
    o.x = off0; o.y = o.x + v.x; o.z = o.y + v.y; o.w = o.z + v.z;
    if (idx + 4 <= Nn) {
        *(int4*)&row_ptr[idx] = o;
        *(int4*)&cnt[idx] = o;
    } else {
        if (idx     < Nn) { row_ptr[idx]     = o.x; cnt[idx]     = o.x; }
        if (idx + 1 < Nn) { row_ptr[idx + 1] = o.y; cnt[idx + 1] = o.y; }
        if (idx + 2 < Nn) { row_ptr[idx + 2] = o.z; cnt[idx + 2] = o.z; }
        if (idx + 3 < Nn) { row_ptr[idx + 3] = o.w; cnt[idx + 3] = o.w; }
    }
}

__global__ void scatter_k(const int* __restrict__ src, const int* __restrict__ dst,
                          int E, int* __restrict__ cursor, int* __restrict__ esrc)
{
    for (int i = blockIdx.x * blockDim.x + threadIdx.x; i < E;
         i += gridDim.x * blockDim.x) {
        int p = atomicAdd(&cursor[dst[i]], 1);
        esrc[p] = src[i];
    }
}

// ============================ edge attention ===============================
__global__ __launch_bounds__(256) void edge_attn_k(
    const unsigned short* __restrict__ Qb, const unsigned short* __restrict__ KVp,
    const int* __restrict__ row_ptr, const int* __restrict__ esrc,
    unsigned short* __restrict__ attnb, int Nn)
{
    const int wave = threadIdx.x >> 6, lane = threadIdx.x & 63;
    const int node = blockIdx.x * 4 + wave;
    if (node >= Nn) return;
    const unsigned qp = *(const unsigned*)&Qb[node * 128 + lane * 2];
    const float qx = b2f((unsigned short)(qp & 0xffff));
    const float qy = b2f((unsigned short)(qp >> 16));
    const int e0 = row_ptr[node], e1 = row_ptr[node + 1];
    const int cnt = e1 - e0;
    int myS = (lane < cnt) ? esrc[e0 + lane] : 0;
    float wv0 = 0.f, wv1 = 0.f, z = 0.f;
    const int n1 = min(cnt, 64);
    int j = 0;
    for (; j + 1 < n1; j += 2) {
        const int s0 = __shfl(myS, j);
        const int s1 = __shfl(myS, j + 1);
        const uint2 kv0 = *(const uint2*)&KVp[(size_t)s0 * 256 + lane * 4];
        const uint2 kv1 = *(const uint2*)&KVp[(size_t)s1 * 256 + lane * 4];
        {
            float p = b2f((unsigned short)(kv0.x & 0xffff)) * qx +
                      b2f((unsigned short)(kv0.x >> 16)) * qy;
            p += __shfl_xor(p, 1); p += __shfl_xor(p, 2); p += __shfl_xor(p, 4);
            const float sc = __expf(fminf(fmaxf(p * 0.25f, -5.f), 5.f));
            wv0 += sc * b2f((unsigned short)(kv0.y & 0xffff));
            wv1 += sc * b2f((unsigned short)(kv0.y >> 16));
            z += sc;
        }
        {
            float p = b2f((unsigned short)(kv1.x & 0xffff)) * qx +
                      b2f((unsigned short)(kv1.x >> 16)) * qy;
            p += __shfl_xor(p, 1); p += __shfl_xor(p, 2); p += __shfl_xor(p, 4);
            const float sc = __expf(fminf(fmaxf(p * 0.25f, -5.f), 5.f));
            wv0 += sc * b2f((unsigned short)(kv1.y & 0xffff));
            wv1 += sc * b2f((unsigned short)(kv1.y >> 16));
            z += sc;
        }
    }
    for (; j < n1; ++j) {
        const int s0 = __shfl(myS, j);
        const uint2 kv0 = *(const uint2*)&KVp[(size_t)s0 * 256 + lane * 4];
        float p = b2f((unsigned short)(kv0.x & 0xffff)) * qx +
                  b2f((unsigned short)(kv0.x >> 16)) * qy;
        p += __shfl_xor(p, 1); p += __shfl_xor(p, 2); p += __shfl_xor(p, 4);
        const float sc = __expf(fminf(fmaxf(p * 0.25f, -5.f), 5.f));
        wv0 += sc * b2f((unsigned short)(kv0.y & 0xffff));
        wv1 += sc * b2f((unsigned short)(kv0.y >> 16));
        z += sc;
    }
    for (int e = e0 + 64; e < e1; ++e) {
        const int s0 = esrc[e];
        const uint2 kv0 = *(const uint2*)&KVp[(size_t)s0 * 256 + lane * 4];
        float p = b2f((unsigned short)(kv0.x & 0xffff)) * qx +
                  b2f((unsigned short)(kv0.x >> 16)) * qy;
        p += __shfl_xor(p, 1); p += __shfl_xor(p, 2); p += __shfl_xor(p, 4);
        const float sc = __expf(fminf(fmaxf(p * 0.25f, -5.f), 5.f));
        wv0 += sc * b2f((unsigned short)(kv0.y & 0xffff));
        wv1 += sc * b2f((unsigned short)(kv0.y >> 16));
        z += sc;
    }
    const float inv = 1.f / z;
    const unsigned outp = (unsigned)f2b(wv0 * inv) | ((unsigned)f2b(wv1 * inv) << 16);
    *(unsigned*)&attnb[node * 128 + lane * 2] = outp;
}

// ============================ BatchNorm ====================================
__global__ void bn_finalize_k(float* __restrict__ stats, const float* __restrict__ gamma,
                              const float* __restrict__ beta, int Nrows)
{
    const int c = threadIdx.x;  // 128 threads
    const float invN = 1.f / (float)Nrows;
    const float mu = stats[c] * invN;
    const float var = stats[128 + c] * invN - mu * mu;
    const float isg = rsqrtf(var + EPS) * gamma[c];
    stats[c] = isg;
    stats[128 + c] = beta[c] - mu * isg;
}

__global__ __launch_bounds__(256) void bn_apply_k(const float* __restrict__ X,
                                                  const float* __restrict__ stats,
                                                  int total4, float* __restrict__ out)
{
    for (int i = blockIdx.x * blockDim.x + threadIdx.x; i < total4;
         i += gridDim.x * blockDim.x) {
        const int c4 = i & 31;
        const float4 sc = ((const float4*)stats)[c4];
        const float4 sh = ((const float4*)stats)[32 + c4];
        float4 v = ((const float4*)X)[i];
        v.x = v.x * sc.x + sh.x;
        v.y = v.y * sc.y + sh.y;
        v.z = v.z * sc.z + sh.z;
        v.w = v.w * sc.w + sh.w;
        ((float4*)out)[i] = v;
    }
}

// ============================ launch =======================================
extern "C" void kernel_launch(void* const* d_in, const int* in_sizes, int n_in,
                              void* d_out, int out_size, void* d_ws, size_t ws_size,
                              hipStream_t stream)
{
    const float* h   = (const float*)d_in[0];
    const float* Wq  = (const float*)d_in[1];
    const float* Wk  = (const float*)d_in[2];
    const float* Wv  = (const float*)d_in[3];
    const float* Wo  = (const float*)d_in[4];
    const float* bo  = (const float*)d_in[5];
    const float* g1  = (const float*)d_in[6];
    const float* b1  = (const float*)d_in[7];
    const float* Wf1 = (const float*)d_in[8];
    const float* bf1 = (const float*)d_in[9];
    const float* Wf2 = (const float*)d_in[10];
    const float* bf2 = (const float*)d_in[11];
    const float* g2  = (const float*)d_in[12];
    const float* b2  = (const float*)d_in[13];
    const int*   src = (const int*)d_in[14];
    const int*   dstv= (const int*)d_in[15];
    const int N = in_sizes[0] / 128;
    const int E = in_sizes[14];

    // ---- workspace layout ----
    unsigned short* Wt = (unsigned short*)d_ws;                        // 131072 bf16
    float* stats1      = (float*)((char*)d_ws + 262144);               // 256 f
    float* stats2      = stats1 + 256;                                 // 256 f
    int* blkSum        = (int*)(stats2 + 256);                         // 256 i
    int* blkOff        = blkSum + 256;                                 // 256 i
    unsigned short* Qb    = (unsigned short*)(blkOff + 256);           // N*128 bf16
    unsigned short* attnb = Qb + (size_t)N * 128;                      // N*128 bf16
    unsigned short* KVp   = attnb + (size_t)N * 128;                   // N*256 bf16
    int* esrc    = (int*)(KVp + (size_t)N * 256);                      // E
    int* cnt     = esrc + E;                                           // N
    int* row_ptr = cnt + N;                                            // N+1
    unsigned short* hidden = Qb;        // N*256 bf16, overlays Qb+attnb (dead)
    float* x = (float*)KVp;             // N*128 fp32, overlays KVp (dead)

    unsigned short* Wf1T = Wt + 65536;  // [256][128]
    unsigned short* Wf2T = Wt + 98304;  // [128][256]

    float* out = (float*)d_out;
    const dim3 b256(256);
    const int gm = (N + 127) / 128;
    const int NB = (N + 1023) / 1024;

    // ---- weight prep ----
    prep_w_k<<<dim3(64),  b256, 0, stream>>>(Wq,  Wt,          128, 128);
    prep_w_k<<<dim3(64),  b256, 0, stream>>>(Wk,  Wt + 16384,  128, 128);
    prep_w_k<<<dim3(64),  b256, 0, stream>>>(Wv,  Wt + 32768,  128, 128);
    prep_w_k<<<dim3(64),  b256, 0, stream>>>(Wo,  Wt + 49152,  128, 128);
    prep_w_k<<<dim3(128), b256, 0, stream>>>(Wf1, Wf1T,        128, 256);
    prep_w_k<<<dim3(128), b256, 0, stream>>>(Wf2, Wf2T,        256, 128);

    // ---- CSR build (multi-block scan) ----
    hipMemsetAsync(cnt, 0, (size_t)N * 4, stream);
    hist_k<<<dim3(2048), b256, 0, stream>>>(dstv, E, cnt);
    part_sum_k<<<dim3(NB), b256, 0, stream>>>(cnt, N, blkSum);
    scan_blk_k<<<dim3(1), b256, 0, stream>>>(blkSum, NB, blkOff, row_ptr, N);
    scan_write_k<<<dim3(NB), b256, 0, stream>>>(cnt, N, blkOff, row_ptr);
    scatter_k<<<dim3(2048), b256, 0, stream>>>(src, dstv, E, cnt, esrc);

    // ---- fused QKV ----
    qkv_k<<<dim3(gm), b256, 0, stream>>>(h, Wt, Qb, KVp, N);

    // ---- sparse attention ----
    edge_attn_k<<<dim3((N + 3) / 4), b256, 0, stream>>>(Qb, KVp, row_ptr, esrc, attnb, N);

    // ---- x = h + attn @ Wo + bo ; accumulate BN1 raw moments ----
    hipMemsetAsync(stats1, 0, 256 * 4, stream);
    mm_k<1, 0, 1, 1><<<dim3(gm, 1), b256, 0, stream>>>(
        attnb, Wt + 49152, bo, h, x, N, 128, 128, 0, nullptr, nullptr, stats1);
    bn_finalize_k<<<dim3(1), dim3(128), 0, stream>>>(stats1, g1, b1, N);

    // ---- FFN1: reads raw x, applies BN1 affine on the fly ----
    mm_k<2, 1, 0, 0><<<dim3(gm, 2), b256, 0, stream>>>(
        x, Wf1T, bf1, nullptr, hidden, N, 128, 256, 1, stats1, nullptr, nullptr);

    // ---- FFN2: resid = BN1(x) on the fly; accumulate BN2 raw moments ----
    hipMemsetAsync(stats2, 0, 256 * 4, stream);
    mm_k<1, 0, 2, 1><<<dim3(gm, 1), b256, 0, stream>>>(
        hidden, Wf2T, bf2, x, out, N, 256, 128, 0, nullptr, stats1, stats2);
    bn_finalize_k<<<dim3(1), dim3(128), 0, stream>>>(stats2, g2, b2, N);

    // ---- BN2 apply in-place on out ----
    bn_apply_k<<<dim3(1024), b256, 0, stream>>>(out, stats2, N * 32, out);
}

// Round 4
// 663.128 us; speedup vs baseline: 1.9186x; 1.1471x over previous
//
#include <hip/hip_runtime.h>

#define EPS 1e-5f

typedef __attribute__((ext_vector_type(8))) short sh8;
typedef __attribute__((ext_vector_type(4))) float f4;

static __device__ __forceinline__ unsigned short f2b(float f) {
    union { float f; unsigned u; } v; v.f = f;
    unsigned r = v.u + 0x7FFF + ((v.u >> 16) & 1);  // RNE
    return (unsigned short)(r >> 16);
}
static __device__ __forceinline__ float b2f(unsigned short b) {
    union { unsigned u; float f; } v; v.u = ((unsigned)b) << 16; return v.f;
}

// ===================== weight prep: fp32 [K][N] -> bf16 [N][K] =============
__global__ __launch_bounds__(256) void prep_w_k(const float* __restrict__ W,
                                                unsigned short* __restrict__ Wt,
                                                int K, int Nc)
{
    int i = blockIdx.x * 256 + threadIdx.x;
    if (i >= K * Nc) return;
    int k = i / Nc, n = i - k * Nc;
    Wt[(size_t)n * K + k] = f2b(W[i]);
}

// ===================== fused QKV GEMM ======================================
__global__ __launch_bounds__(256) void qkv_k(
    const float* __restrict__ h, const unsigned short* __restrict__ Wt,
    unsigned short* __restrict__ Qb, unsigned short* __restrict__ KVp, int M)
{
    __shared__ __align__(16) unsigned short As[128 * 136];
    __shared__ __align__(16) unsigned short Ws[128 * 72];
    const int tid = threadIdx.x;
    const int wave = tid >> 6, lane = tid & 63;
    const int q = lane >> 4, lm = lane & 15;
    const int rowBase = blockIdx.x * 128;
    const int r0 = (wave & 1) * 64, c0 = (wave >> 1) * 64;

#pragma unroll
    for (int j = 0; j < 16; ++j) {
        int idx = tid + j * 256;
        int row = idx >> 5, kk = (idx & 31) * 4;
        int grow = rowBase + row;
        float4 v = make_float4(0.f, 0.f, 0.f, 0.f);
        if (grow < M) v = *(const float4*)&h[(size_t)grow * 128 + kk];
        ushort4 b;
        b.x = f2b(v.x); b.y = f2b(v.y); b.z = f2b(v.z); b.w = f2b(v.w);
        *(ushort4*)&As[row * 136 + kk] = b;
    }

    for (int w = 0; w < 3; ++w) {
        f4 acc[4][4];
#pragma unroll
        for (int mi = 0; mi < 4; ++mi)
#pragma unroll
            for (int ni = 0; ni < 4; ++ni) {
                f4 z = {0.f, 0.f, 0.f, 0.f};
                acc[mi][ni] = z;
            }
        for (int kc = 0; kc < 2; ++kc) {
#pragma unroll
            for (int j = 0; j < 4; ++j) {
                int idx = tid + j * 256;
                int n = idx >> 3, kk = (idx & 7) * 8;
                uint4 v = *(const uint4*)&Wt[(size_t)w * 16384 + (size_t)n * 128 + kc * 64 + kk];
                *(uint4*)&Ws[n * 72 + kk] = v;
            }
            __syncthreads();
#pragma unroll
            for (int k2 = 0; k2 < 2; ++k2) {
                sh8 af[4], bfr[4];
#pragma unroll
                for (int t = 0; t < 4; ++t) {
                    af[t]  = *(const sh8*)&As[(r0 + t * 16 + lm) * 136 + kc * 64 + k2 * 32 + q * 8];
                    bfr[t] = *(const sh8*)&Ws[(c0 + t * 16 + lm) * 72 + k2 * 32 + q * 8];
                }
#pragma unroll
                for (int mi = 0; mi < 4; ++mi)
#pragma unroll
                    for (int ni = 0; ni < 4; ++ni)
                        acc[mi][ni] = __builtin_amdgcn_mfma_f32_16x16x32_bf16(
                            af[mi], bfr[ni], acc[mi][ni], 0, 0, 0);
            }
            __syncthreads();
        }
        const int slot = (w == 2) ? 2 : 0;
#pragma unroll
        for (int mi = 0; mi < 4; ++mi)
#pragma unroll
            for (int ni = 0; ni < 4; ++ni) {
                const int col = c0 + ni * 16 + lm;
#pragma unroll
                for (int r = 0; r < 4; ++r) {
                    int grow = rowBase + r0 + mi * 16 + q * 4 + r;
                    if (grow >= M) continue;
                    unsigned short b = f2b(acc[mi][ni][r]);
                    if (w == 0)
                        Qb[(size_t)grow * 128 + col] = b;
                    else
                        KVp[(size_t)grow * 256 + ((col >> 1) << 2) + (col & 1) + slot] = b;
                }
            }
    }
}

// ===================== MFMA GEMM ===========================================
template<int AMODE, int OMODE, int RESMODE, int STATS>
__global__ __launch_bounds__(256) void mm_k(
    const void* __restrict__ Ap, const unsigned short* __restrict__ Wt,
    const float* __restrict__ bias, const float* __restrict__ resid,
    void* __restrict__ Cp, int M, int Kdim, int ldc, int relu,
    const float* __restrict__ astats, const float* __restrict__ sstats,
    float* __restrict__ ostats)
{
    __shared__ __align__(16) unsigned short As[128 * 72];
    __shared__ __align__(16) unsigned short Ws[128 * 72];
    const int tid = threadIdx.x;
    const int wave = tid >> 6, lane = tid & 63;
    const int q = lane >> 4, lm = lane & 15;
    const int rowBase = blockIdx.x * 128;
    const int colBase = blockIdx.y * 128;
    const unsigned short* Wblk = Wt + (size_t)colBase * Kdim;
    const int r0 = (wave & 1) * 64, c0 = (wave >> 1) * 64;

    f4 acc[4][4];
#pragma unroll
    for (int mi = 0; mi < 4; ++mi)
#pragma unroll
        for (int ni = 0; ni < 4; ++ni) {
            f4 z = {0.f, 0.f, 0.f, 0.f};
            acc[mi][ni] = z;
        }

    for (int kc = 0; kc < Kdim; kc += 64) {
        if (AMODE == 1) {
            const unsigned short* A = (const unsigned short*)Ap;
#pragma unroll
            for (int j = 0; j < 4; ++j) {
                int idx = tid + j * 256;
                int row = idx >> 3, kk = (idx & 7) * 8;
                int grow = rowBase + row;
                uint4 v = make_uint4(0u, 0u, 0u, 0u);
                if (grow < M) v = *(const uint4*)&A[(size_t)grow * Kdim + kc + kk];
                *(uint4*)&As[row * 72 + kk] = v;
            }
        } else {
            const float* A = (const float*)Ap;
#pragma unroll
            for (int j = 0; j < 8; ++j) {
                int idx = tid + j * 256;
                int row = idx >> 4, kk = (idx & 15) * 4;
                int grow = rowBase + row;
                float4 v = make_float4(0.f, 0.f, 0.f, 0.f);
                if (grow < M) v = *(const float4*)&A[(size_t)grow * Kdim + kc + kk];
                if (AMODE == 2) {
                    const int f = kc + kk;
                    const float4 sc = *(const float4*)&astats[f];
                    const float4 sh = *(const float4*)&astats[128 + f];
                    v.x = v.x * sc.x + sh.x; v.y = v.y * sc.y + sh.y;
                    v.z = v.z * sc.z + sh.z; v.w = v.w * sc.w + sh.w;
                }
                ushort4 b;
                b.x = f2b(v.x); b.y = f2b(v.y); b.z = f2b(v.z); b.w = f2b(v.w);
                *(ushort4*)&As[row * 72 + kk] = b;
            }
        }
#pragma unroll
        for (int j = 0; j < 4; ++j) {
            int idx = tid + j * 256;
            int n = idx >> 3, kk = (idx & 7) * 8;
            uint4 v = *(const uint4*)&Wblk[(size_t)n * Kdim + kc + kk];
            *(uint4*)&Ws[n * 72 + kk] = v;
        }
        __syncthreads();
#pragma unroll
        for (int k2 = 0; k2 < 2; ++k2) {
            sh8 af[4], bfr[4];
#pragma unroll
            for (int t = 0; t < 4; ++t) {
                af[t]  = *(const sh8*)&As[(r0 + t * 16 + lm) * 72 + k2 * 32 + q * 8];
                bfr[t] = *(const sh8*)&Ws[(c0 + t * 16 + lm) * 72 + k2 * 32 + q * 8];
            }
#pragma unroll
            for (int mi = 0; mi < 4; ++mi)
#pragma unroll
                for (int ni = 0; ni < 4; ++ni)
                    acc[mi][ni] = __builtin_amdgcn_mfma_f32_16x16x32_bf16(
                        af[mi], bfr[ni], acc[mi][ni], 0, 0, 0);
        }
        __syncthreads();
    }

#pragma unroll
    for (int ni = 0; ni < 4; ++ni) {
        const int gcol = colBase + c0 + ni * 16 + lm;
        const float bv = bias ? bias[gcol] : 0.f;
        float s = 0.f, ss = 0.f;
#pragma unroll
        for (int mi = 0; mi < 4; ++mi) {
#pragma unroll
            for (int r = 0; r < 4; ++r) {
                int grow = rowBase + r0 + mi * 16 + q * 4 + r;
                if (grow >= M) continue;
                float val = acc[mi][ni][r] + bv;
                if (RESMODE == 1) val += resid[(size_t)grow * ldc + gcol];
                if (RESMODE == 2) val += resid[(size_t)grow * ldc + gcol] * sstats[gcol] + sstats[128 + gcol];
                if (relu) val = fmaxf(val, 0.f);
                if (STATS) { s += val; ss += val * val; }
                if (OMODE == 0) ((float*)Cp)[(size_t)grow * ldc + gcol] = val;
                else ((unsigned short*)Cp)[(size_t)grow * ldc + gcol] = f2b(val);
            }
        }
        if (STATS) {
            s += __shfl_xor(s, 16); s += __shfl_xor(s, 32);
            ss += __shfl_xor(ss, 16); ss += __shfl_xor(ss, 32);
            if (q == 0) {
                atomicAdd(&ostats[gcol], s);
                atomicAdd(&ostats[128 + gcol], ss);
            }
        }
    }
}

// ============== CSR build: two-level LDS counting sort =====================
// Bucket = dst >> 8 (256 nodes / bucket). Packed entry = (dst&255)<<17 | src.
// Requires N <= 131072 (src fits 17 bits).

__global__ __launch_bounds__(256) void bucket_cnt_k(const int* __restrict__ dst,
                                                    int E, int* __restrict__ bCnt)
{
    __shared__ int c[512];
    const int t = threadIdx.x;
    c[t] = 0; c[t + 256] = 0;
    __syncthreads();
    for (int i = blockIdx.x * 256 + t; i < E; i += gridDim.x * 256)
        atomicAdd(&c[dst[i] >> 8], 1);
    __syncthreads();
    if (c[t]) atomicAdd(&bCnt[t], c[t]);
    if (c[t + 256]) atomicAdd(&bCnt[t + 256], c[t + 256]);
}

__global__ __launch_bounds__(512) void bucket_scan_k(const int* __restrict__ bCnt,
                                                     int B, int* __restrict__ bOff,
                                                     int* __restrict__ bCur)
{
    __shared__ int ts[512];
    const int t = threadIdx.x;
    const int v = (t < B) ? bCnt[t] : 0;
    ts[t] = v;
    __syncthreads();
    for (int o = 1; o < 512; o <<= 1) {
        int u = (t >= o) ? ts[t - o] : 0;
        __syncthreads();
        ts[t] += u;
        __syncthreads();
    }
    const int ex = ts[t] - v;
    if (t < B) { bOff[t] = ex; bCur[t] = ex; }
    if (t == B - 1) bOff[B] = ex + v;
}

#define CCH 8192
__global__ __launch_bounds__(512) void coarse_k(const int* __restrict__ src,
                                                const int* __restrict__ dst, int E,
                                                int* __restrict__ bCur,
                                                unsigned* __restrict__ coarse)
{
    __shared__ int cnt[512], off[512], gbase[512], rc[512];
    __shared__ unsigned pk[CCH];
    __shared__ int ga[CCH];
    const int t = threadIdx.x;
    const int e0 = blockIdx.x * CCH;
    const int n = min(CCH, E - e0);
    cnt[t] = 0;
    __syncthreads();
    for (int i = t; i < n; i += 512) atomicAdd(&cnt[dst[e0 + i] >> 8], 1);
    __syncthreads();
    const int v = cnt[t];
    off[t] = v;
    __syncthreads();
    for (int o = 1; o < 512; o <<= 1) {
        int u = (t >= o) ? off[t - o] : 0;
        __syncthreads();
        off[t] += u;
        __syncthreads();
    }
    const int ex = off[t] - v;
    off[t] = ex;                        // own-slot rewrite, no cross-read yet
    if (v > 0) gbase[t] = atomicAdd(&bCur[t], v);
    rc[t] = 0;
    __syncthreads();
    for (int i = t; i < n; i += 512) {
        const int d = dst[e0 + i], s = src[e0 + i];
        const int b = d >> 8;
        const int j = atomicAdd(&rc[b], 1);
        const int slot = off[b] + j;
        pk[slot] = ((unsigned)(d & 255) << 17) | (unsigned)s;
        ga[slot] = gbase[b] + j;
    }
    __syncthreads();
    for (int i = t; i < n; i += 512) coarse[ga[i]] = pk[i];
}

__global__ __launch_bounds__(256) void fine_k(const unsigned* __restrict__ coarse,
                                              const int* __restrict__ bOff, int B,
                                              int Nn, int* __restrict__ row_ptr,
                                              int* __restrict__ esrc)
{
    __shared__ int cnt[256], off[256], rc[256];
    const int t = threadIdx.x;
    const int b = blockIdx.x;
    const int base = b << 8;
    const int e0 = bOff[b], e1 = bOff[b + 1];
    cnt[t] = 0;
    __syncthreads();
    for (int i = e0 + t; i < e1; i += 256)
        atomicAdd(&cnt[(coarse[i] >> 17) & 255], 1);
    __syncthreads();
    const int v = cnt[t];
    off[t] = v;
    __syncthreads();
    for (int o = 1; o < 256; o <<= 1) {
        int u = (t >= o) ? off[t - o] : 0;
        __syncthreads();
        off[t] += u;
        __syncthreads();
    }
    const int ex = off[t] - v;
    off[t] = ex;
    rc[t] = 0;
    if (base + t < Nn) row_ptr[base + t] = e0 + ex;
    if (b == B - 1 && t == 0) row_ptr[Nn] = e1;
    __syncthreads();
    for (int i = e0 + t; i < e1; i += 256) {
        const unsigned p = coarse[i];
        const int l = (p >> 17) & 255;
        const int j = atomicAdd(&rc[l], 1);
        esrc[e0 + off[l] + j] = (int)(p & 0x1FFFFu);
    }
}

// ============================ edge attention ===============================
__global__ __launch_bounds__(256) void edge_attn_k(
    const unsigned short* __restrict__ Qb, const unsigned short* __restrict__ KVp,
    const int* __restrict__ row_ptr, const int* __restrict__ esrc,
    unsigned short* __restrict__ attnb, int Nn)
{
    const int wave = threadIdx.x >> 6, lane = threadIdx.x & 63;
    const int node = blockIdx.x * 4 + wave;
    if (node >= Nn) return;
    const unsigned qp = *(const unsigned*)&Qb[node * 128 + lane * 2];
    const float qx = b2f((unsigned short)(qp & 0xffff));
    const float qy = b2f((unsigned short)(qp >> 16));
    const int e0 = row_ptr[node], e1 = row_ptr[node + 1];
    const int cnt = e1 - e0;
    int myS = (lane < cnt) ? esrc[e0 + lane] : 0;
    float wv0 = 0.f, wv1 = 0.f, z = 0.f;
    const int n1 = min(cnt, 64);
    int j = 0;
    for (; j + 1 < n1; j += 2) {
        const int s0 = __shfl(myS, j);
        const int s1 = __shfl(myS, j + 1);
        const uint2 kv0 = *(const uint2*)&KVp[(size_t)s0 * 256 + lane * 4];
        const uint2 kv1 = *(const uint2*)&KVp[(size_t)s1 * 256 + lane * 4];
        {
            float p = b2f((unsigned short)(kv0.x & 0xffff)) * qx +
                      b2f((unsigned short)(kv0.x >> 16)) * qy;
            p += __shfl_xor(p, 1); p += __shfl_xor(p, 2); p += __shfl_xor(p, 4);
            const float sc = __expf(fminf(fmaxf(p * 0.25f, -5.f), 5.f));
            wv0 += sc * b2f((unsigned short)(kv0.y & 0xffff));
            wv1 += sc * b2f((unsigned short)(kv0.y >> 16));
            z += sc;
        }
        {
            float p = b2f((unsigned short)(kv1.x & 0xffff)) * qx +
                      b2f((unsigned short)(kv1.x >> 16)) * qy;
            p += __shfl_xor(p, 1); p += __shfl_xor(p, 2); p += __shfl_xor(p, 4);
            const float sc = __expf(fminf(fmaxf(p * 0.25f, -5.f), 5.f));
            wv0 += sc * b2f((unsigned short)(kv1.y & 0xffff));
            wv1 += sc * b2f((unsigned short)(kv1.y >> 16));
            z += sc;
        }
    }
    for (; j < n1; ++j) {
        const int s0 = __shfl(myS, j);
        const uint2 kv0 = *(const uint2*)&KVp[(size_t)s0 * 256 + lane * 4];
        float p = b2f((unsigned short)(kv0.x & 0xffff)) * qx +
                  b2f((unsigned short)(kv0.x >> 16)) * qy;
        p += __shfl_xor(p, 1); p += __shfl_xor(p, 2); p += __shfl_xor(p, 4);
        const float sc = __expf(fminf(fmaxf(p * 0.25f, -5.f), 5.f));
        wv0 += sc * b2f((unsigned short)(kv0.y & 0xffff));
        wv1 += sc * b2f((unsigned short)(kv0.y >> 16));
        z += sc;
    }
    for (int e = e0 + 64; e < e1; ++e) {
        const int s0 = esrc[e];
        const uint2 kv0 = *(const uint2*)&KVp[(size_t)s0 * 256 + lane * 4];
        float p = b2f((unsigned short)(kv0.x & 0xffff)) * qx +
                  b2f((unsigned short)(kv0.x >> 16)) * qy;
        p += __shfl_xor(p, 1); p += __shfl_xor(p, 2); p += __shfl_xor(p, 4);
        const float sc = __expf(fminf(fmaxf(p * 0.25f, -5.f), 5.f));
        wv0 += sc * b2f((unsigned short)(kv0.y & 0xffff));
        wv1 += sc * b2f((unsigned short)(kv0.y >> 16));
        z += sc;
    }
    const float inv = 1.f / z;
    const unsigned outp = (unsigned)f2b(wv0 * inv) | ((unsigned)f2b(wv1 * inv) << 16);
    *(unsigned*)&attnb[node * 128 + lane * 2] = outp;
}

// ============================ BatchNorm ====================================
__global__ void bn_finalize_k(float* __restrict__ stats, const float* __restrict__ gamma,
                              const float* __restrict__ beta, int Nrows)
{
    const int c = threadIdx.x;  // 128 threads
    const float invN = 1.f / (float)Nrows;
    const float mu = stats[c] * invN;
    const float var = stats[128 + c] * invN - mu * mu;
    const float isg = rsqrtf(var + EPS) * gamma[c];
    stats[c] = isg;
    stats[128 + c] = beta[c] - mu * isg;
}

__global__ __launch_bounds__(256) void bn_apply_k(const float* __restrict__ X,
                                                  const float* __restrict__ stats,
                                                  int total4, float* __restrict__ out)
{
    for (int i = blockIdx.x * blockDim.x + threadIdx.x; i < total4;
         i += gridDim.x * blockDim.x) {
        const int c4 = i & 31;
        const float4 sc = ((const float4*)stats)[c4];
        const float4 sh = ((const float4*)stats)[32 + c4];
        float4 v = ((const float4*)X)[i];
        v.x = v.x * sc.x + sh.x;
        v.y = v.y * sc.y + sh.y;
        v.z = v.z * sc.z + sh.z;
        v.w = v.w * sc.w + sh.w;
        ((float4*)out)[i] = v;
    }
}

// ============================ launch =======================================
extern "C" void kernel_launch(void* const* d_in, const int* in_sizes, int n_in,
                              void* d_out, int out_size, void* d_ws, size_t ws_size,
                              hipStream_t stream)
{
    const float* h   = (const float*)d_in[0];
    const float* Wq  = (const float*)d_in[1];
    const float* Wk  = (const float*)d_in[2];
    const float* Wv  = (const float*)d_in[3];
    const float* Wo  = (const float*)d_in[4];
    const float* bo  = (const float*)d_in[5];
    const float* g1  = (const float*)d_in[6];
    const float* b1  = (const float*)d_in[7];
    const float* Wf1 = (const float*)d_in[8];
    const float* bf1 = (const float*)d_in[9];
    const float* Wf2 = (const float*)d_in[10];
    const float* bf2 = (const float*)d_in[11];
    const float* g2  = (const float*)d_in[12];
    const float* b2  = (const float*)d_in[13];
    const int*   src = (const int*)d_in[14];
    const int*   dstv= (const int*)d_in[15];
    const int N = in_sizes[0] / 128;
    const int E = in_sizes[14];
    const int B = (N + 255) >> 8;   // coarse buckets (<=512 for N<=131072)

    // ---- workspace layout ----
    unsigned short* Wt = (unsigned short*)d_ws;                        // 131072 bf16
    float* stats1      = (float*)((char*)d_ws + 262144);               // 256 f
    float* stats2      = stats1 + 256;                                 // 256 f
    int* bCnt          = (int*)(stats2 + 256);                         // 512 i
    int* bOff          = bCnt + 512;                                   // 513 i
    int* bCur          = bOff + 513;                                   // 512 i
    unsigned short* Qb    = (unsigned short*)(bCur + 512 + 3);         // N*128 bf16
    unsigned short* attnb = Qb + (size_t)N * 128;                      // N*128 bf16
    unsigned short* KVp   = attnb + (size_t)N * 128;                   // N*256 bf16
    int* esrc      = (int*)(KVp + (size_t)N * 256);                    // E
    unsigned* coarse = (unsigned*)(esrc + E);                          // E
    int* row_ptr   = (int*)(coarse + E);                               // N+1
    unsigned short* hidden = Qb;        // N*256 bf16, overlays Qb+attnb (dead)
    float* x = (float*)KVp;             // N*128 fp32, overlays KVp (dead)

    unsigned short* Wf1T = Wt + 65536;  // [256][128]
    unsigned short* Wf2T = Wt + 98304;  // [128][256]

    float* out = (float*)d_out;
    const dim3 b256(256);
    const int gm = (N + 127) / 128;

    // ---- weight prep ----
    prep_w_k<<<dim3(64),  b256, 0, stream>>>(Wq,  Wt,          128, 128);
    prep_w_k<<<dim3(64),  b256, 0, stream>>>(Wk,  Wt + 16384,  128, 128);
    prep_w_k<<<dim3(64),  b256, 0, stream>>>(Wv,  Wt + 32768,  128, 128);
    prep_w_k<<<dim3(64),  b256, 0, stream>>>(Wo,  Wt + 49152,  128, 128);
    prep_w_k<<<dim3(128), b256, 0, stream>>>(Wf1, Wf1T,        128, 256);
    prep_w_k<<<dim3(128), b256, 0, stream>>>(Wf2, Wf2T,        256, 128);

    // ---- CSR build via two-level counting sort ----
    hipMemsetAsync(bCnt, 0, 512 * 4, stream);
    bucket_cnt_k<<<dim3(256), b256, 0, stream>>>(dstv, E, bCnt);
    bucket_scan_k<<<dim3(1), dim3(512), 0, stream>>>(bCnt, B, bOff, bCur);
    coarse_k<<<dim3((E + CCH - 1) / CCH), dim3(512), 0, stream>>>(src, dstv, E, bCur, coarse);
    fine_k<<<dim3(B), b256, 0, stream>>>(coarse, bOff, B, N, row_ptr, esrc);

    // ---- fused QKV ----
    qkv_k<<<dim3(gm), b256, 0, stream>>>(h, Wt, Qb, KVp, N);

    // ---- sparse attention ----
    edge_attn_k<<<dim3((N + 3) / 4), b256, 0, stream>>>(Qb, KVp, row_ptr, esrc, attnb, N);

    // ---- x = h + attn @ Wo + bo ; accumulate BN1 raw moments ----
    hipMemsetAsync(stats1, 0, 256 * 4, stream);
    mm_k<1, 0, 1, 1><<<dim3(gm, 1), b256, 0, stream>>>(
        attnb, Wt + 49152, bo, h, x, N, 128, 128, 0, nullptr, nullptr, stats1);
    bn_finalize_k<<<dim3(1), dim3(128), 0, stream>>>(stats1, g1, b1, N);

    // ---- FFN1: reads raw x, applies BN1 affine on the fly ----
    mm_k<2, 1, 0, 0><<<dim3(gm, 2), b256, 0, stream>>>(
        x, Wf1T, bf1, nullptr, hidden, N, 128, 256, 1, stats1, nullptr, nullptr);

    // ---- FFN2: resid = BN1(x) on the fly; accumulate BN2 raw moments ----
    hipMemsetAsync(stats2, 0, 256 * 4, stream);
    mm_k<1, 0, 2, 1><<<dim3(gm, 1), b256, 0, stream>>>(
        hidden, Wf2T, bf2, x, out, N, 256, 128, 0, nullptr, stats1, stats2);
    bn_finalize_k<<<dim3(1), dim3(128), 0, stream>>>(stats2, g2, b2, N);

    // ---- BN2 apply in-place on out ----
    bn_apply_k<<<dim3(1024), b256, 0, stream>>>(out, stats2, N * 32, out);
}

// Round 5
// 557.773 us; speedup vs baseline: 2.2810x; 1.1889x over previous
//
#include <hip/hip_runtime.h>

#define EPS 1e-5f
#define VSCALE 20.0f

typedef __attribute__((ext_vector_type(8))) short sh8;
typedef __attribute__((ext_vector_type(4))) float f4;
typedef __attribute__((ext_vector_type(2))) _Float16 h2f;

static __device__ __forceinline__ unsigned short f2b(float f) {
    union { float f; unsigned u; } v; v.f = f;
    unsigned r = v.u + 0x7FFF + ((v.u >> 16) & 1);  // RNE
    return (unsigned short)(r >> 16);
}
static __device__ __forceinline__ float b2f(unsigned short b) {
    union { unsigned u; float f; } v; v.u = ((unsigned)b) << 16; return v.f;
}
static __device__ __forceinline__ unsigned pk2(float a, float b) {
    return (unsigned)f2b(a) | ((unsigned)f2b(b) << 16);
}
static __device__ __forceinline__ float dot2h(h2f a, h2f b) {
#if __has_builtin(__builtin_amdgcn_fdot2)
    return __builtin_amdgcn_fdot2(a, b, 0.f, false);
#else
    return (float)a.x * (float)b.x + (float)a.y * (float)b.y;
#endif
}

// ===================== weight prep (all 6, one launch) =====================
// squares: Wt[s*16384 + n*128 + k]; Wf1: +65536 [n*128+k]; Wf2: +98304 [n*256+k]
__global__ __launch_bounds__(256) void prep_all_k(
    const float* __restrict__ Wq, const float* __restrict__ Wk,
    const float* __restrict__ Wv, const float* __restrict__ Wo,
    const float* __restrict__ Wf1, const float* __restrict__ Wf2,
    unsigned short* __restrict__ Wt)
{
    int i = blockIdx.x * 256 + threadIdx.x;      // 0..131071
    if (i < 65536) {
        int s = i >> 14;
        const float* W = (s == 0) ? Wq : (s == 1) ? Wk : (s == 2) ? Wv : Wo;
        int l = i & 16383, k = l >> 7, n = l & 127;
        Wt[(i & ~16383) + n * 128 + k] = f2b(W[l]);
    } else if (i < 98304) {
        int l = i - 65536, k = l >> 8, n = l & 255;
        Wt[65536 + n * 128 + k] = f2b(Wf1[l]);
    } else {
        int l = i - 98304, k = l >> 7, n = l & 127;
        Wt[98304 + n * 256 + k] = f2b(Wf2[l]);
    }
}

// ===================== fused QKV GEMM ======================================
// Outputs: Qh f16 [N][128], Kh f16 [N][128], V8 int8(x20) [N][128]
__global__ __launch_bounds__(256) void qkv_k(
    const float* __restrict__ h, const unsigned short* __restrict__ Wt,
    _Float16* __restrict__ Qh, _Float16* __restrict__ Kh,
    signed char* __restrict__ V8, int M)
{
    __shared__ __align__(16) unsigned short As[128 * 136];
    __shared__ __align__(16) unsigned short Ws[128 * 72];
    const int tid = threadIdx.x;
    const int wave = tid >> 6, lane = tid & 63;
    const int q = lane >> 4, lm = lane & 15;
    const int rowBase = blockIdx.x * 128;
    const int r0 = (wave & 1) * 64, c0 = (wave >> 1) * 64;

#pragma unroll
    for (int j = 0; j < 16; ++j) {
        int idx = tid + j * 256;
        int row = idx >> 5, kk = (idx & 31) * 4;
        int grow = rowBase + row;
        float4 v = make_float4(0.f, 0.f, 0.f, 0.f);
        if (grow < M) v = *(const float4*)&h[(size_t)grow * 128 + kk];
        ushort4 b;
        b.x = f2b(v.x); b.y = f2b(v.y); b.z = f2b(v.z); b.w = f2b(v.w);
        *(ushort4*)&As[row * 136 + kk] = b;
    }

    for (int w = 0; w < 3; ++w) {
        f4 acc[4][4];
#pragma unroll
        for (int mi = 0; mi < 4; ++mi)
#pragma unroll
            for (int ni = 0; ni < 4; ++ni) {
                f4 z = {0.f, 0.f, 0.f, 0.f};
                acc[mi][ni] = z;
            }
        for (int kc = 0; kc < 2; ++kc) {
#pragma unroll
            for (int j = 0; j < 4; ++j) {
                int idx = tid + j * 256;
                int n = idx >> 3, kk = (idx & 7) * 8;
                uint4 v = *(const uint4*)&Wt[(size_t)w * 16384 + (size_t)n * 128 + kc * 64 + kk];
                *(uint4*)&Ws[n * 72 + kk] = v;
            }
            __syncthreads();
#pragma unroll
            for (int k2 = 0; k2 < 2; ++k2) {
                sh8 af[4], bfr[4];
#pragma unroll
                for (int t = 0; t < 4; ++t) {
                    af[t]  = *(const sh8*)&As[(r0 + t * 16 + lm) * 136 + kc * 64 + k2 * 32 + q * 8];
                    bfr[t] = *(const sh8*)&Ws[(c0 + t * 16 + lm) * 72 + k2 * 32 + q * 8];
                }
#pragma unroll
                for (int mi = 0; mi < 4; ++mi)
#pragma unroll
                    for (int ni = 0; ni < 4; ++ni)
                        acc[mi][ni] = __builtin_amdgcn_mfma_f32_16x16x32_bf16(
                            af[mi], bfr[ni], acc[mi][ni], 0, 0, 0);
            }
            __syncthreads();
        }
#pragma unroll
        for (int mi = 0; mi < 4; ++mi)
#pragma unroll
            for (int ni = 0; ni < 4; ++ni) {
                const int col = c0 + ni * 16 + lm;
#pragma unroll
                for (int r = 0; r < 4; ++r) {
                    int grow = rowBase + r0 + mi * 16 + q * 4 + r;
                    if (grow >= M) continue;
                    const float v = acc[mi][ni][r];
                    if (w == 0) Qh[(size_t)grow * 128 + col] = (_Float16)v;
                    else if (w == 1) Kh[(size_t)grow * 128 + col] = (_Float16)v;
                    else {
                        float t = rintf(v * VSCALE);
                        t = fminf(fmaxf(t, -127.f), 127.f);
                        V8[(size_t)grow * 128 + col] = (signed char)(int)t;
                    }
                }
            }
    }
}

// ===================== MFMA GEMM ===========================================
// AMODE: 1 bf16 A, 3 bf16 A + affine astats (BN apply on read)
// OMODE: 0 fp32 out, 1 bf16 out
// RESMODE: 0 none, 1 fp32 resid, 3 bf16 resid + affine sstats
// STATS: accumulate per-column sum/sumsq of output into ostats
template<int AMODE, int OMODE, int RESMODE, int STATS>
__global__ __launch_bounds__(256) void mm_k(
    const void* __restrict__ Ap, const unsigned short* __restrict__ Wt,
    const float* __restrict__ bias, const void* __restrict__ resid,
    void* __restrict__ Cp, int M, int Kdim, int ldc, int relu,
    const float* __restrict__ astats, const float* __restrict__ sstats,
    float* __restrict__ ostats)
{
    __shared__ __align__(16) unsigned short As[128 * 72];
    __shared__ __align__(16) unsigned short Ws[128 * 72];
    const int tid = threadIdx.x;
    const int wave = tid >> 6, lane = tid & 63;
    const int q = lane >> 4, lm = lane & 15;
    const int rowBase = blockIdx.x * 128;
    const int colBase = blockIdx.y * 128;
    const unsigned short* Wblk = Wt + (size_t)colBase * Kdim;
    const int r0 = (wave & 1) * 64, c0 = (wave >> 1) * 64;

    f4 acc[4][4];
#pragma unroll
    for (int mi = 0; mi < 4; ++mi)
#pragma unroll
        for (int ni = 0; ni < 4; ++ni) {
            f4 z = {0.f, 0.f, 0.f, 0.f};
            acc[mi][ni] = z;
        }

    for (int kc = 0; kc < Kdim; kc += 64) {
        const unsigned short* A = (const unsigned short*)Ap;
#pragma unroll
        for (int j = 0; j < 4; ++j) {
            int idx = tid + j * 256;
            int row = idx >> 3, kk = (idx & 7) * 8;
            int grow = rowBase + row;
            uint4 v = make_uint4(0u, 0u, 0u, 0u);
            if (grow < M) v = *(const uint4*)&A[(size_t)grow * Kdim + kc + kk];
            if (AMODE == 3) {
                const int f = kc + kk;
                const float4 sc0 = *(const float4*)&astats[f];
                const float4 sc1 = *(const float4*)&astats[f + 4];
                const float4 sh0 = *(const float4*)&astats[128 + f];
                const float4 sh1 = *(const float4*)&astats[128 + f + 4];
                uint4 o;
                o.x = pk2(b2f((unsigned short)(v.x & 0xffff)) * sc0.x + sh0.x,
                          b2f((unsigned short)(v.x >> 16)) * sc0.y + sh0.y);
                o.y = pk2(b2f((unsigned short)(v.y & 0xffff)) * sc0.z + sh0.z,
                          b2f((unsigned short)(v.y >> 16)) * sc0.w + sh0.w);
                o.z = pk2(b2f((unsigned short)(v.z & 0xffff)) * sc1.x + sh1.x,
                          b2f((unsigned short)(v.z >> 16)) * sc1.y + sh1.y);
                o.w = pk2(b2f((unsigned short)(v.w & 0xffff)) * sc1.z + sh1.z,
                          b2f((unsigned short)(v.w >> 16)) * sc1.w + sh1.w);
                v = o;
            }
            *(uint4*)&As[row * 72 + kk] = v;
        }
#pragma unroll
        for (int j = 0; j < 4; ++j) {
            int idx = tid + j * 256;
            int n = idx >> 3, kk = (idx & 7) * 8;
            uint4 v = *(const uint4*)&Wblk[(size_t)n * Kdim + kc + kk];
            *(uint4*)&Ws[n * 72 + kk] = v;
        }
        __syncthreads();
#pragma unroll
        for (int k2 = 0; k2 < 2; ++k2) {
            sh8 af[4], bfr[4];
#pragma unroll
            for (int t = 0; t < 4; ++t) {
                af[t]  = *(const sh8*)&As[(r0 + t * 16 + lm) * 72 + k2 * 32 + q * 8];
                bfr[t] = *(const sh8*)&Ws[(c0 + t * 16 + lm) * 72 + k2 * 32 + q * 8];
            }
#pragma unroll
            for (int mi = 0; mi < 4; ++mi)
#pragma unroll
                for (int ni = 0; ni < 4; ++ni)
                    acc[mi][ni] = __builtin_amdgcn_mfma_f32_16x16x32_bf16(
                        af[mi], bfr[ni], acc[mi][ni], 0, 0, 0);
        }
        __syncthreads();
    }

#pragma unroll
    for (int ni = 0; ni < 4; ++ni) {
        const int gcol = colBase + c0 + ni * 16 + lm;
        const float bv = bias ? bias[gcol] : 0.f;
        float s = 0.f, ss = 0.f;
#pragma unroll
        for (int mi = 0; mi < 4; ++mi) {
#pragma unroll
            for (int r = 0; r < 4; ++r) {
                int grow = rowBase + r0 + mi * 16 + q * 4 + r;
                if (grow >= M) continue;
                float val = acc[mi][ni][r] + bv;
                if (RESMODE == 1)
                    val += ((const float*)resid)[(size_t)grow * ldc + gcol];
                if (RESMODE == 3)
                    val += b2f(((const unsigned short*)resid)[(size_t)grow * ldc + gcol])
                           * sstats[gcol] + sstats[128 + gcol];
                if (relu) val = fmaxf(val, 0.f);
                if (STATS) { s += val; ss += val * val; }
                if (OMODE == 0) ((float*)Cp)[(size_t)grow * ldc + gcol] = val;
                else ((unsigned short*)Cp)[(size_t)grow * ldc + gcol] = f2b(val);
            }
        }
        if (STATS) {
            s += __shfl_xor(s, 16); s += __shfl_xor(s, 32);
            ss += __shfl_xor(ss, 16); ss += __shfl_xor(ss, 32);
            if (q == 0) {
                atomicAdd(&ostats[gcol], s);
                atomicAdd(&ostats[128 + gcol], ss);
            }
        }
    }
}

// ============== CSR build: two-level LDS counting sort =====================
__global__ __launch_bounds__(256) void bucket_cnt_k(const int* __restrict__ dst,
                                                    int E, int* __restrict__ bCnt)
{
    __shared__ int c[512];
    const int t = threadIdx.x;
    c[t] = 0; c[t + 256] = 0;
    __syncthreads();
    for (int i = blockIdx.x * 256 + t; i < E; i += gridDim.x * 256)
        atomicAdd(&c[dst[i] >> 8], 1);
    __syncthreads();
    if (c[t]) atomicAdd(&bCnt[t], c[t]);
    if (c[t + 256]) atomicAdd(&bCnt[t + 256], c[t + 256]);
}

__global__ __launch_bounds__(512) void bucket_scan_k(const int* __restrict__ bCnt,
                                                     int B, int* __restrict__ bOff,
                                                     int* __restrict__ bCur)
{
    __shared__ int ts[512];
    const int t = threadIdx.x;
    const int v = (t < B) ? bCnt[t] : 0;
    ts[t] = v;
    __syncthreads();
    for (int o = 1; o < 512; o <<= 1) {
        int u = (t >= o) ? ts[t - o] : 0;
        __syncthreads();
        ts[t] += u;
        __syncthreads();
    }
    const int ex = ts[t] - v;
    if (t < B) { bOff[t] = ex; bCur[t] = ex; }
    if (t == B - 1) bOff[B] = ex + v;
}

#define CCH 8192
__global__ __launch_bounds__(512) void coarse_k(const int* __restrict__ src,
                                                const int* __restrict__ dst, int E,
                                                int* __restrict__ bCur,
                                                unsigned* __restrict__ coarse)
{
    __shared__ int cnt[512], off[512], gbase[512], rc[512];
    __shared__ unsigned pk[CCH];
    __shared__ int ga[CCH];
    const int t = threadIdx.x;
    const int e0 = blockIdx.x * CCH;
    const int n = min(CCH, E - e0);
    cnt[t] = 0;
    __syncthreads();
    for (int i = t; i < n; i += 512) atomicAdd(&cnt[dst[e0 + i] >> 8], 1);
    __syncthreads();
    const int v = cnt[t];
    off[t] = v;
    __syncthreads();
    for (int o = 1; o < 512; o <<= 1) {
        int u = (t >= o) ? off[t - o] : 0;
        __syncthreads();
        off[t] += u;
        __syncthreads();
    }
    const int ex = off[t] - v;
    off[t] = ex;
    if (v > 0) gbase[t] = atomicAdd(&bCur[t], v);
    rc[t] = 0;
    __syncthreads();
    for (int i = t; i < n; i += 512) {
        const int d = dst[e0 + i], s = src[e0 + i];
        const int b = d >> 8;
        const int j = atomicAdd(&rc[b], 1);
        const int slot = off[b] + j;
        pk[slot] = ((unsigned)(d & 255) << 17) | (unsigned)s;
        ga[slot] = gbase[b] + j;
    }
    __syncthreads();
    for (int i = t; i < n; i += 512) coarse[ga[i]] = pk[i];
}

__global__ __launch_bounds__(256) void fine_k(const unsigned* __restrict__ coarse,
                                              const int* __restrict__ bOff, int B,
                                              int Nn, int* __restrict__ row_ptr,
                                              int* __restrict__ esrc)
{
    __shared__ int cnt[256], off[256], rc[256];
    const int t = threadIdx.x;
    const int b = blockIdx.x;
    const int base = b << 8;
    const int e0 = bOff[b], e1 = bOff[b + 1];
    cnt[t] = 0;
    __syncthreads();
    for (int i = e0 + t; i < e1; i += 256)
        atomicAdd(&cnt[(coarse[i] >> 17) & 255], 1);
    __syncthreads();
    const int v = cnt[t];
    off[t] = v;
    __syncthreads();
    for (int o = 1; o < 256; o <<= 1) {
        int u = (t >= o) ? off[t - o] : 0;
        __syncthreads();
        off[t] += u;
        __syncthreads();
    }
    const int ex = off[t] - v;
    off[t] = ex;
    rc[t] = 0;
    if (base + t < Nn) row_ptr[base + t] = e0 + ex;
    if (b == B - 1 && t == 0) row_ptr[Nn] = e1;
    __syncthreads();
    for (int i = e0 + t; i < e1; i += 256) {
        const unsigned p = coarse[i];
        const int l = (p >> 17) & 255;
        const int j = atomicAdd(&rc[l], 1);
        esrc[e0 + off[l] + j] = (int)(p & 0x1FFFFu);
    }
}

// ============================ edge attention ===============================
// Lane l owns dims (2l, 2l+1); head = l>>3. K f16 (dot2), V int8 (x VSCALE).
__global__ __launch_bounds__(256) void edge_attn_k(
    const _Float16* __restrict__ Qh, const _Float16* __restrict__ Kh,
    const signed char* __restrict__ V8, const int* __restrict__ row_ptr,
    const int* __restrict__ esrc, unsigned short* __restrict__ attnb, int Nn)
{
    const int wave = threadIdx.x >> 6, lane = threadIdx.x & 63;
    const int node = blockIdx.x * 4 + wave;
    if (node >= Nn) return;
    const h2f q2 = *(const h2f*)&Qh[(size_t)node * 128 + lane * 2];
    const int e0 = row_ptr[node], e1 = row_ptr[node + 1];
    const int cnt = e1 - e0;
    int myS = (lane < cnt) ? esrc[e0 + lane] : 0;
    float wv0 = 0.f, wv1 = 0.f, z = 0.f;
    const int n1 = min(cnt, 64);
    int j = 0;
    for (; j + 1 < n1; j += 2) {
        const int s0 = __shfl(myS, j);
        const int s1 = __shfl(myS, j + 1);
        const h2f k0 = *(const h2f*)&Kh[(size_t)s0 * 128 + lane * 2];
        const h2f k1 = *(const h2f*)&Kh[(size_t)s1 * 128 + lane * 2];
        const char2 v0 = *(const char2*)&V8[(size_t)s0 * 128 + lane * 2];
        const char2 v1 = *(const char2*)&V8[(size_t)s1 * 128 + lane * 2];
        {
            float p = dot2h(k0, q2);
            p += __shfl_xor(p, 1); p += __shfl_xor(p, 2); p += __shfl_xor(p, 4);
            const float sc = __expf(fminf(fmaxf(p * 0.25f, -5.f), 5.f));
            wv0 += sc * (float)v0.x;
            wv1 += sc * (float)v0.y;
            z += sc;
        }
        {
            float p = dot2h(k1, q2);
            p += __shfl_xor(p, 1); p += __shfl_xor(p, 2); p += __shfl_xor(p, 4);
            const float sc = __expf(fminf(fmaxf(p * 0.25f, -5.f), 5.f));
            wv0 += sc * (float)v1.x;
            wv1 += sc * (float)v1.y;
            z += sc;
        }
    }
    for (; j < n1; ++j) {
        const int s0 = __shfl(myS, j);
        const h2f k0 = *(const h2f*)&Kh[(size_t)s0 * 128 + lane * 2];
        const char2 v0 = *(const char2*)&V8[(size_t)s0 * 128 + lane * 2];
        float p = dot2h(k0, q2);
        p += __shfl_xor(p, 1); p += __shfl_xor(p, 2); p += __shfl_xor(p, 4);
        const float sc = __expf(fminf(fmaxf(p * 0.25f, -5.f), 5.f));
        wv0 += sc * (float)v0.x;
        wv1 += sc * (float)v0.y;
        z += sc;
    }
    for (int e = e0 + 64; e < e1; ++e) {     // rare: deg > 64
        const int s0 = esrc[e];
        const h2f k0 = *(const h2f*)&Kh[(size_t)s0 * 128 + lane * 2];
        const char2 v0 = *(const char2*)&V8[(size_t)s0 * 128 + lane * 2];
        float p = dot2h(k0, q2);
        p += __shfl_xor(p, 1); p += __shfl_xor(p, 2); p += __shfl_xor(p, 4);
        const float sc = __expf(fminf(fmaxf(p * 0.25f, -5.f), 5.f));
        wv0 += sc * (float)v0.x;
        wv1 += sc * (float)v0.y;
        z += sc;
    }
    const float inv = 1.f / (z * VSCALE);
    *(unsigned*)&attnb[(size_t)node * 128 + lane * 2] = pk2(wv0 * inv, wv1 * inv);
}

// ============================ BatchNorm ====================================
__global__ void bn_finalize_k(float* __restrict__ stats, const float* __restrict__ gamma,
                              const float* __restrict__ beta, int Nrows)
{
    const int c = threadIdx.x;  // 128 threads
    const float invN = 1.f / (float)Nrows;
    const float mu = stats[c] * invN;
    const float var = stats[128 + c] * invN - mu * mu;
    const float isg = rsqrtf(var + EPS) * gamma[c];
    stats[c] = isg;
    stats[128 + c] = beta[c] - mu * isg;
}

__global__ __launch_bounds__(256) void bn_apply_k(const float* __restrict__ X,
                                                  const float* __restrict__ stats,
                                                  int total4, float* __restrict__ out)
{
    for (int i = blockIdx.x * blockDim.x + threadIdx.x; i < total4;
         i += gridDim.x * blockDim.x) {
        const int c4 = i & 31;
        const float4 sc = ((const float4*)stats)[c4];
        const float4 sh = ((const float4*)stats)[32 + c4];
        float4 v = ((const float4*)X)[i];
        v.x = v.x * sc.x + sh.x;
        v.y = v.y * sc.y + sh.y;
        v.z = v.z * sc.z + sh.z;
        v.w = v.w * sc.w + sh.w;
        ((float4*)out)[i] = v;
    }
}

// ============================ launch =======================================
extern "C" void kernel_launch(void* const* d_in, const int* in_sizes, int n_in,
                              void* d_out, int out_size, void* d_ws, size_t ws_size,
                              hipStream_t stream)
{
    const float* h   = (const float*)d_in[0];
    const float* Wq  = (const float*)d_in[1];
    const float* Wk  = (const float*)d_in[2];
    const float* Wv  = (const float*)d_in[3];
    const float* Wo  = (const float*)d_in[4];
    const float* bo  = (const float*)d_in[5];
    const float* g1  = (const float*)d_in[6];
    const float* b1  = (const float*)d_in[7];
    const float* Wf1 = (const float*)d_in[8];
    const float* bf1 = (const float*)d_in[9];
    const float* Wf2 = (const float*)d_in[10];
    const float* bf2 = (const float*)d_in[11];
    const float* g2  = (const float*)d_in[12];
    const float* b2  = (const float*)d_in[13];
    const int*   src = (const int*)d_in[14];
    const int*   dstv= (const int*)d_in[15];
    const int N = in_sizes[0] / 128;
    const int E = in_sizes[14];
    const int B = (N + 255) >> 8;

    // ---- workspace layout ----
    unsigned short* Wt = (unsigned short*)d_ws;               // 131072 bf16
    float* stats1 = (float*)((char*)d_ws + 262144);           // 256
    float* stats2 = stats1 + 256;                             // 256
    int* bCnt = (int*)(stats2 + 256);                         // 512
    int* bOff = bCnt + 512;                                   // 513
    int* bCur = bOff + 513;                                   // 512
    uintptr_t big = ((uintptr_t)(bCur + 512) + 255) & ~(uintptr_t)255;
    _Float16* Qh = (_Float16*)big;                            // N*128 f16
    _Float16* Kh = Qh + (size_t)N * 128;                      // N*128 f16
    signed char* V8 = (signed char*)(Kh + (size_t)N * 128);   // N*128 i8
    uintptr_t a2 = ((uintptr_t)(V8 + (size_t)N * 128) + 255) & ~(uintptr_t)255;
    unsigned short* attnb = (unsigned short*)a2;              // N*128 bf16
    unsigned short* xb = attnb + (size_t)N * 128;             // N*128 bf16
    int* row_ptr = (int*)(xb + (size_t)N * 128);              // N+1
    // overlays (lifetimes disjoint):
    unsigned* coarse = (unsigned*)attnb;   // written d5, read d6; attnb born d8
    int* esrc = (int*)xb;                  // written d6, read d8; xb born d9
    unsigned short* hidden = (unsigned short*)Qh;  // N*256; Qh/Kh dead after d8

    unsigned short* Wf1T = Wt + 65536;
    unsigned short* Wf2T = Wt + 98304;

    float* out = (float*)d_out;
    const dim3 b256(256);
    const int gm = (N + 127) / 128;

    // ---- one memset for stats1|stats2|bCnt ----
    hipMemsetAsync(stats1, 0, 4096, stream);

    // ---- weight prep (one launch) ----
    prep_all_k<<<dim3(512), b256, 0, stream>>>(Wq, Wk, Wv, Wo, Wf1, Wf2, Wt);

    // ---- CSR build via two-level counting sort ----
    bucket_cnt_k<<<dim3(256), b256, 0, stream>>>(dstv, E, bCnt);
    bucket_scan_k<<<dim3(1), dim3(512), 0, stream>>>(bCnt, B, bOff, bCur);
    coarse_k<<<dim3((E + CCH - 1) / CCH), dim3(512), 0, stream>>>(src, dstv, E, bCur, coarse);
    fine_k<<<dim3(B), b256, 0, stream>>>(coarse, bOff, B, N, row_ptr, esrc);

    // ---- fused QKV (f16 Q/K, int8 V) ----
    qkv_k<<<dim3(gm), b256, 0, stream>>>(h, Wt, Qh, Kh, V8, N);

    // ---- sparse attention -> attnb bf16 ----
    edge_attn_k<<<dim3((N + 3) / 4), b256, 0, stream>>>(Qh, Kh, V8, row_ptr, esrc, attnb, N);

    // ---- x = h + attn @ Wo + bo (bf16 out) ; BN1 raw moments ----
    mm_k<1, 1, 1, 1><<<dim3(gm, 1), b256, 0, stream>>>(
        attnb, Wt + 49152, bo, h, xb, N, 128, 128, 0, nullptr, nullptr, stats1);
    bn_finalize_k<<<dim3(1), dim3(128), 0, stream>>>(stats1, g1, b1, N);

    // ---- FFN1: bf16 x + BN1 affine on read -> hidden bf16, relu ----
    mm_k<3, 1, 0, 0><<<dim3(gm, 2), b256, 0, stream>>>(
        xb, Wf1T, bf1, nullptr, hidden, N, 128, 256, 1, stats1, nullptr, nullptr);

    // ---- FFN2: resid = BN1(x) bf16-affine; BN2 raw moments -> out fp32 ----
    mm_k<1, 0, 3, 1><<<dim3(gm, 1), b256, 0, stream>>>(
        hidden, Wf2T, bf2, xb, out, N, 256, 128, 0, nullptr, stats1, stats2);
    bn_finalize_k<<<dim3(1), dim3(128), 0, stream>>>(stats2, g2, b2, N);

    // ---- BN2 apply in-place on out ----
    bn_apply_k<<<dim3(1024), b256, 0, stream>>>(out, stats2, N * 32, out);
}

// Round 6
// 544.142 us; speedup vs baseline: 2.3381x; 1.0251x over previous
//
#include <hip/hip_runtime.h>

#define EPS 1e-5f
#define VSCALE 20.0f

typedef __attribute__((ext_vector_type(8))) short sh8;
typedef __attribute__((ext_vector_type(4))) float f4;
typedef __attribute__((ext_vector_type(2))) _Float16 h2f;

static __device__ __forceinline__ unsigned short f2b(float f) {
    union { float f; unsigned u; } v; v.f = f;
    unsigned r = v.u + 0x7FFF + ((v.u >> 16) & 1);  // RNE
    return (unsigned short)(r >> 16);
}
static __device__ __forceinline__ float b2f(unsigned short b) {
    union { unsigned u; float f; } v; v.u = ((unsigned)b) << 16; return v.f;
}
static __device__ __forceinline__ unsigned pk2(float a, float b) {
    return (unsigned)f2b(a) | ((unsigned)f2b(b) << 16);
}
static __device__ __forceinline__ float dot2h(h2f a, h2f b, float c) {
#if __has_builtin(__builtin_amdgcn_fdot2)
    return __builtin_amdgcn_fdot2(a, b, c, false);
#else
    return (float)a.x * (float)b.x + (float)a.y * (float)b.y + c;
#endif
}

// ===================== weight prep (all 6, one launch) =====================
__global__ __launch_bounds__(256) void prep_all_k(
    const float* __restrict__ Wq, const float* __restrict__ Wk,
    const float* __restrict__ Wv, const float* __restrict__ Wo,
    const float* __restrict__ Wf1, const float* __restrict__ Wf2,
    unsigned short* __restrict__ Wt)
{
    int i = blockIdx.x * 256 + threadIdx.x;      // 0..131071
    if (i < 65536) {
        int s = i >> 14;
        const float* W = (s == 0) ? Wq : (s == 1) ? Wk : (s == 2) ? Wv : Wo;
        int l = i & 16383, k = l >> 7, n = l & 127;
        Wt[(i & ~16383) + n * 128 + k] = f2b(W[l]);
    } else if (i < 98304) {
        int l = i - 65536, k = l >> 8, n = l & 255;
        Wt[65536 + n * 128 + k] = f2b(Wf1[l]);
    } else {
        int l = i - 98304, k = l >> 7, n = l & 127;
        Wt[98304 + n * 256 + k] = f2b(Wf2[l]);
    }
}

// ===================== fused QKV GEMM ======================================
// Outputs: Qh f16 [N][128], Kh f16 [N][128], V8u uint8 biased (v*20+128)
__global__ __launch_bounds__(256) void qkv_k(
    const float* __restrict__ h, const unsigned short* __restrict__ Wt,
    _Float16* __restrict__ Qh, _Float16* __restrict__ Kh,
    unsigned char* __restrict__ V8u, int M)
{
    __shared__ __align__(16) unsigned short As[128 * 136];
    __shared__ __align__(16) unsigned short Ws[128 * 72];
    const int tid = threadIdx.x;
    const int wave = tid >> 6, lane = tid & 63;
    const int q = lane >> 4, lm = lane & 15;
    const int rowBase = blockIdx.x * 128;
    const int r0 = (wave & 1) * 64, c0 = (wave >> 1) * 64;

#pragma unroll
    for (int j = 0; j < 16; ++j) {
        int idx = tid + j * 256;
        int row = idx >> 5, kk = (idx & 31) * 4;
        int grow = rowBase + row;
        float4 v = make_float4(0.f, 0.f, 0.f, 0.f);
        if (grow < M) v = *(const float4*)&h[(size_t)grow * 128 + kk];
        ushort4 b;
        b.x = f2b(v.x); b.y = f2b(v.y); b.z = f2b(v.z); b.w = f2b(v.w);
        *(ushort4*)&As[row * 136 + kk] = b;
    }

    for (int w = 0; w < 3; ++w) {
        f4 acc[4][4];
#pragma unroll
        for (int mi = 0; mi < 4; ++mi)
#pragma unroll
            for (int ni = 0; ni < 4; ++ni) {
                f4 z = {0.f, 0.f, 0.f, 0.f};
                acc[mi][ni] = z;
            }
        for (int kc = 0; kc < 2; ++kc) {
#pragma unroll
            for (int j = 0; j < 4; ++j) {
                int idx = tid + j * 256;
                int n = idx >> 3, kk = (idx & 7) * 8;
                uint4 v = *(const uint4*)&Wt[(size_t)w * 16384 + (size_t)n * 128 + kc * 64 + kk];
                *(uint4*)&Ws[n * 72 + kk] = v;
            }
            __syncthreads();
#pragma unroll
            for (int k2 = 0; k2 < 2; ++k2) {
                sh8 af[4], bfr[4];
#pragma unroll
                for (int t = 0; t < 4; ++t) {
                    af[t]  = *(const sh8*)&As[(r0 + t * 16 + lm) * 136 + kc * 64 + k2 * 32 + q * 8];
                    bfr[t] = *(const sh8*)&Ws[(c0 + t * 16 + lm) * 72 + k2 * 32 + q * 8];
                }
#pragma unroll
                for (int mi = 0; mi < 4; ++mi)
#pragma unroll
                    for (int ni = 0; ni < 4; ++ni)
                        acc[mi][ni] = __builtin_amdgcn_mfma_f32_16x16x32_bf16(
                            af[mi], bfr[ni], acc[mi][ni], 0, 0, 0);
            }
            __syncthreads();
        }
#pragma unroll
        for (int mi = 0; mi < 4; ++mi)
#pragma unroll
            for (int ni = 0; ni < 4; ++ni) {
                const int col = c0 + ni * 16 + lm;
#pragma unroll
                for (int r = 0; r < 4; ++r) {
                    int grow = rowBase + r0 + mi * 16 + q * 4 + r;
                    if (grow >= M) continue;
                    const float v = acc[mi][ni][r];
                    if (w == 0) Qh[(size_t)grow * 128 + col] = (_Float16)v;
                    else if (w == 1) Kh[(size_t)grow * 128 + col] = (_Float16)v;
                    else {
                        float t = rintf(v * VSCALE);
                        t = fminf(fmaxf(t, -127.f), 127.f);
                        V8u[(size_t)grow * 128 + col] = (unsigned char)(int)(t + 128.f);
                    }
                }
            }
    }
}

// ===================== MFMA GEMM ===========================================
// AMODE: 1 bf16 A, 3 bf16 A + affine astats (BN apply on read)
// OMODE: 0 fp32 out, 1 bf16 out
// RESMODE: 0 none, 1 fp32 resid, 3 bf16 resid + affine sstats
// STATS: accumulate per-column sum/sumsq of output into ostats
template<int AMODE, int OMODE, int RESMODE, int STATS>
__global__ __launch_bounds__(256) void mm_k(
    const void* __restrict__ Ap, const unsigned short* __restrict__ Wt,
    const float* __restrict__ bias, const void* __restrict__ resid,
    void* __restrict__ Cp, int M, int Kdim, int ldc, int relu,
    const float* __restrict__ astats, const float* __restrict__ sstats,
    float* __restrict__ ostats)
{
    __shared__ __align__(16) unsigned short As[128 * 72];
    __shared__ __align__(16) unsigned short Ws[128 * 72];
    const int tid = threadIdx.x;
    const int wave = tid >> 6, lane = tid & 63;
    const int q = lane >> 4, lm = lane & 15;
    const int rowBase = blockIdx.x * 128;
    const int colBase = blockIdx.y * 128;
    const unsigned short* Wblk = Wt + (size_t)colBase * Kdim;
    const int r0 = (wave & 1) * 64, c0 = (wave >> 1) * 64;

    f4 acc[4][4];
#pragma unroll
    for (int mi = 0; mi < 4; ++mi)
#pragma unroll
        for (int ni = 0; ni < 4; ++ni) {
            f4 z = {0.f, 0.f, 0.f, 0.f};
            acc[mi][ni] = z;
        }

    for (int kc = 0; kc < Kdim; kc += 64) {
        const unsigned short* A = (const unsigned short*)Ap;
#pragma unroll
        for (int j = 0; j < 4; ++j) {
            int idx = tid + j * 256;
            int row = idx >> 3, kk = (idx & 7) * 8;
            int grow = rowBase + row;
            uint4 v = make_uint4(0u, 0u, 0u, 0u);
            if (grow < M) v = *(const uint4*)&A[(size_t)grow * Kdim + kc + kk];
            if (AMODE == 3) {
                const int f = kc + kk;
                const float4 sc0 = *(const float4*)&astats[f];
                const float4 sc1 = *(const float4*)&astats[f + 4];
                const float4 sh0 = *(const float4*)&astats[128 + f];
                const float4 sh1 = *(const float4*)&astats[128 + f + 4];
                uint4 o;
                o.x = pk2(b2f((unsigned short)(v.x & 0xffff)) * sc0.x + sh0.x,
                          b2f((unsigned short)(v.x >> 16)) * sc0.y + sh0.y);
                o.y = pk2(b2f((unsigned short)(v.y & 0xffff)) * sc0.z + sh0.z,
                          b2f((unsigned short)(v.y >> 16)) * sc0.w + sh0.w);
                o.z = pk2(b2f((unsigned short)(v.z & 0xffff)) * sc1.x + sh1.x,
                          b2f((unsigned short)(v.z >> 16)) * sc1.y + sh1.y);
                o.w = pk2(b2f((unsigned short)(v.w & 0xffff)) * sc1.z + sh1.z,
                          b2f((unsigned short)(v.w >> 16)) * sc1.w + sh1.w);
                v = o;
            }
            *(uint4*)&As[row * 72 + kk] = v;
        }
#pragma unroll
        for (int j = 0; j < 4; ++j) {
            int idx = tid + j * 256;
            int n = idx >> 3, kk = (idx & 7) * 8;
            uint4 v = *(const uint4*)&Wblk[(size_t)n * Kdim + kc + kk];
            *(uint4*)&Ws[n * 72 + kk] = v;
        }
        __syncthreads();
#pragma unroll
        for (int k2 = 0; k2 < 2; ++k2) {
            sh8 af[4], bfr[4];
#pragma unroll
            for (int t = 0; t < 4; ++t) {
                af[t]  = *(const sh8*)&As[(r0 + t * 16 + lm) * 72 + k2 * 32 + q * 8];
                bfr[t] = *(const sh8*)&Ws[(c0 + t * 16 + lm) * 72 + k2 * 32 + q * 8];
            }
#pragma unroll
            for (int mi = 0; mi < 4; ++mi)
#pragma unroll
                for (int ni = 0; ni < 4; ++ni)
                    acc[mi][ni] = __builtin_amdgcn_mfma_f32_16x16x32_bf16(
                        af[mi], bfr[ni], acc[mi][ni], 0, 0, 0);
        }
        __syncthreads();
    }

#pragma unroll
    for (int ni = 0; ni < 4; ++ni) {
        const int gcol = colBase + c0 + ni * 16 + lm;
        const float bv = bias ? bias[gcol] : 0.f;
        float s = 0.f, ss = 0.f;
#pragma unroll
        for (int mi = 0; mi < 4; ++mi) {
#pragma unroll
            for (int r = 0; r < 4; ++r) {
                int grow = rowBase + r0 + mi * 16 + q * 4 + r;
                if (grow >= M) continue;
                float val = acc[mi][ni][r] + bv;
                if (RESMODE == 1)
                    val += ((const float*)resid)[(size_t)grow * ldc + gcol];
                if (RESMODE == 3)
                    val += b2f(((const unsigned short*)resid)[(size_t)grow * ldc + gcol])
                           * sstats[gcol] + sstats[128 + gcol];
                if (relu) val = fmaxf(val, 0.f);
                if (STATS) { s += val; ss += val * val; }
                if (OMODE == 0) ((float*)Cp)[(size_t)grow * ldc + gcol] = val;
                else ((unsigned short*)Cp)[(size_t)grow * ldc + gcol] = f2b(val);
            }
        }
        if (STATS) {
            s += __shfl_xor(s, 16); s += __shfl_xor(s, 32);
            ss += __shfl_xor(ss, 16); ss += __shfl_xor(ss, 32);
            if (q == 0) {
                atomicAdd(&ostats[gcol], s);
                atomicAdd(&ostats[128 + gcol], ss);
            }
        }
    }
}

// ============== CSR build: two-level LDS counting sort =====================
__global__ __launch_bounds__(256) void bucket_cnt_k(const int* __restrict__ dst,
                                                    int E, int* __restrict__ bCnt)
{
    __shared__ int c[512];
    const int t = threadIdx.x;
    c[t] = 0; c[t + 256] = 0;
    __syncthreads();
    for (int i = blockIdx.x * 256 + t; i < E; i += gridDim.x * 256)
        atomicAdd(&c[dst[i] >> 8], 1);
    __syncthreads();
    if (c[t]) atomicAdd(&bCnt[t], c[t]);
    if (c[t + 256]) atomicAdd(&bCnt[t + 256], c[t + 256]);
}

__global__ __launch_bounds__(512) void bucket_scan_k(const int* __restrict__ bCnt,
                                                     int B, int* __restrict__ bOff,
                                                     int* __restrict__ bCur)
{
    __shared__ int ts[512];
    const int t = threadIdx.x;
    const int v = (t < B) ? bCnt[t] : 0;
    ts[t] = v;
    __syncthreads();
    for (int o = 1; o < 512; o <<= 1) {
        int u = (t >= o) ? ts[t - o] : 0;
        __syncthreads();
        ts[t] += u;
        __syncthreads();
    }
    const int ex = ts[t] - v;
    if (t < B) { bOff[t] = ex; bCur[t] = ex; }
    if (t == B - 1) bOff[B] = ex + v;
}

#define CCH 8192
__global__ __launch_bounds__(512) void coarse_k(const int* __restrict__ src,
                                                const int* __restrict__ dst, int E,
                                                int* __restrict__ bCur,
                                                unsigned* __restrict__ coarse)
{
    __shared__ int cnt[512], off[512], gbase[512], rc[512];
    __shared__ unsigned pk[CCH];
    __shared__ int ga[CCH];
    const int t = threadIdx.x;
    const int e0 = blockIdx.x * CCH;
    const int n = min(CCH, E - e0);
    cnt[t] = 0;
    __syncthreads();
    for (int i = t; i < n; i += 512) atomicAdd(&cnt[dst[e0 + i] >> 8], 1);
    __syncthreads();
    const int v = cnt[t];
    off[t] = v;
    __syncthreads();
    for (int o = 1; o < 512; o <<= 1) {
        int u = (t >= o) ? off[t - o] : 0;
        __syncthreads();
        off[t] += u;
        __syncthreads();
    }
    const int ex = off[t] - v;
    off[t] = ex;
    if (v > 0) gbase[t] = atomicAdd(&bCur[t], v);
    rc[t] = 0;
    __syncthreads();
    for (int i = t; i < n; i += 512) {
        const int d = dst[e0 + i], s = src[e0 + i];
        const int b = d >> 8;
        const int j = atomicAdd(&rc[b], 1);
        const int slot = off[b] + j;
        pk[slot] = ((unsigned)(d & 255) << 17) | (unsigned)s;
        ga[slot] = gbase[b] + j;
    }
    __syncthreads();
    for (int i = t; i < n; i += 512) coarse[ga[i]] = pk[i];
}

__global__ __launch_bounds__(256) void fine_k(const unsigned* __restrict__ coarse,
                                              const int* __restrict__ bOff, int B,
                                              int Nn, int* __restrict__ row_ptr,
                                              int* __restrict__ esrc)
{
    __shared__ int cnt[256], off[256], rc[256];
    const int t = threadIdx.x;
    const int b = blockIdx.x;
    const int base = b << 8;
    const int e0 = bOff[b], e1 = bOff[b + 1];
    cnt[t] = 0;
    __syncthreads();
    for (int i = e0 + t; i < e1; i += 256)
        atomicAdd(&cnt[(coarse[i] >> 17) & 255], 1);
    __syncthreads();
    const int v = cnt[t];
    off[t] = v;
    __syncthreads();
    for (int o = 1; o < 256; o <<= 1) {
        int u = (t >= o) ? off[t - o] : 0;
        __syncthreads();
        off[t] += u;
        __syncthreads();
    }
    const int ex = off[t] - v;
    off[t] = ex;
    rc[t] = 0;
    if (base + t < Nn) row_ptr[base + t] = e0 + ex;
    if (b == B - 1 && t == 0) row_ptr[Nn] = e1;
    __syncthreads();
    for (int i = e0 + t; i < e1; i += 256) {
        const unsigned p = coarse[i];
        const int l = (p >> 17) & 255;
        const int j = atomicAdd(&rc[l], 1);
        esrc[e0 + off[l] + j] = (int)(p & 0x1FFFFu);
    }
}

// ============================ edge attention ===============================
// Wave per node. lane = (p = l>>5 edge-parity, g = l&31 dim-group).
// Lane owns dims 4g..4g+3 of edge j+p. Head = g>>2; score reduce over 4 lanes.
// K f16 (fdot2), V biased uint8 (true = u - 128, scaled by VSCALE).
__global__ __launch_bounds__(256) void edge_attn_k(
    const _Float16* __restrict__ Qh, const _Float16* __restrict__ Kh,
    const unsigned char* __restrict__ V8u, const int* __restrict__ row_ptr,
    const int* __restrict__ esrc, unsigned short* __restrict__ attnb, int Nn)
{
    const int wave = threadIdx.x >> 6, lane = threadIdx.x & 63;
    const int node = blockIdx.x * 4 + wave;
    if (node >= Nn) return;
    const int g = lane & 31, p = lane >> 5;
    const h2f q0 = *(const h2f*)&Qh[(size_t)node * 128 + g * 4];
    const h2f q1 = *(const h2f*)&Qh[(size_t)node * 128 + g * 4 + 2];
    const int e0 = row_ptr[node], e1 = row_ptr[node + 1];
    const int cnt = e1 - e0;
    float a0 = 0.f, a1 = 0.f, a2 = 0.f, a3 = 0.f, z = 0.f;
    for (int base = 0; base < cnt; base += 64) {
        const int nb = min(cnt - base, 64);
        const int myS = (lane < nb) ? esrc[e0 + base + lane] : 0;
        for (int j = 0; j < nb; j += 2) {
            const int ei = j + p;
            const int s = __shfl(myS, ei);        // ds_bpermute, per-lane idx
            const h2f k0 = *(const h2f*)&Kh[(size_t)s * 128 + g * 4];
            const h2f k1 = *(const h2f*)&Kh[(size_t)s * 128 + g * 4 + 2];
            float sp = dot2h(k1, q1, dot2h(k0, q0, 0.f));
            sp += __shfl_xor(sp, 1);
            sp += __shfl_xor(sp, 2);              // full 16-dim head dot
            float sc = __expf(fminf(fmaxf(sp * 0.25f, -5.f), 5.f));
            sc = (ei < nb) ? sc : 0.f;
            const unsigned vv = *(const unsigned*)&V8u[(size_t)s * 128 + g * 4];
            a0 += sc * (float)(vv & 0xffu);
            a1 += sc * (float)((vv >> 8) & 0xffu);
            a2 += sc * (float)((vv >> 16) & 0xffu);
            a3 += sc * (float)(vv >> 24);
            z += sc;
        }
    }
    // combine edge-parity halves
    a0 += __shfl_xor(a0, 32);
    a1 += __shfl_xor(a1, 32);
    a2 += __shfl_xor(a2, 32);
    a3 += __shfl_xor(a3, 32);
    z  += __shfl_xor(z, 32);
    const float inv = 1.f / (z * VSCALE);
    const float c = 128.f * z;
    if (p == 0) {
        uint2 o;
        o.x = pk2((a0 - c) * inv, (a1 - c) * inv);
        o.y = pk2((a2 - c) * inv, (a3 - c) * inv);
        *(uint2*)&attnb[(size_t)node * 128 + g * 4] = o;
    }
}

// ============================ BatchNorm ====================================
__global__ void bn_finalize_k(float* __restrict__ stats, const float* __restrict__ gamma,
                              const float* __restrict__ beta, int Nrows)
{
    const int c = threadIdx.x;  // 128 threads
    const float invN = 1.f / (float)Nrows;
    const float mu = stats[c] * invN;
    const float var = stats[128 + c] * invN - mu * mu;
    const float isg = rsqrtf(var + EPS) * gamma[c];
    stats[c] = isg;
    stats[128 + c] = beta[c] - mu * isg;
}

// reads bf16 X, writes fp32 out; 8 elems/thread
__global__ __launch_bounds__(256) void bn_apply_b_k(const unsigned short* __restrict__ X,
                                                    const float* __restrict__ stats,
                                                    int total8, float* __restrict__ out)
{
    for (int i = blockIdx.x * blockDim.x + threadIdx.x; i < total8;
         i += gridDim.x * blockDim.x) {
        const int c8 = (i & 15) * 8;
        const float4 sc0 = *(const float4*)&stats[c8];
        const float4 sc1 = *(const float4*)&stats[c8 + 4];
        const float4 sh0 = *(const float4*)&stats[128 + c8];
        const float4 sh1 = *(const float4*)&stats[128 + c8 + 4];
        const uint4 v = ((const uint4*)X)[i];
        float4 o0, o1;
        o0.x = b2f((unsigned short)(v.x & 0xffff)) * sc0.x + sh0.x;
        o0.y = b2f((unsigned short)(v.x >> 16))    * sc0.y + sh0.y;
        o0.z = b2f((unsigned short)(v.y & 0xffff)) * sc0.z + sh0.z;
        o0.w = b2f((unsigned short)(v.y >> 16))    * sc0.w + sh0.w;
        o1.x = b2f((unsigned short)(v.z & 0xffff)) * sc1.x + sh1.x;
        o1.y = b2f((unsigned short)(v.z >> 16))    * sc1.y + sh1.y;
        o1.z = b2f((unsigned short)(v.w & 0xffff)) * sc1.z + sh1.z;
        o1.w = b2f((unsigned short)(v.w >> 16))    * sc1.w + sh1.w;
        ((float4*)out)[i * 2]     = o0;
        ((float4*)out)[i * 2 + 1] = o1;
    }
}

// ============================ launch =======================================
extern "C" void kernel_launch(void* const* d_in, const int* in_sizes, int n_in,
                              void* d_out, int out_size, void* d_ws, size_t ws_size,
                              hipStream_t stream)
{
    const float* h   = (const float*)d_in[0];
    const float* Wq  = (const float*)d_in[1];
    const float* Wk  = (const float*)d_in[2];
    const float* Wv  = (const float*)d_in[3];
    const float* Wo  = (const float*)d_in[4];
    const float* bo  = (const float*)d_in[5];
    const float* g1  = (const float*)d_in[6];
    const float* b1  = (const float*)d_in[7];
    const float* Wf1 = (const float*)d_in[8];
    const float* bf1 = (const float*)d_in[9];
    const float* Wf2 = (const float*)d_in[10];
    const float* bf2 = (const float*)d_in[11];
    const float* g2  = (const float*)d_in[12];
    const float* b2  = (const float*)d_in[13];
    const int*   src = (const int*)d_in[14];
    const int*   dstv= (const int*)d_in[15];
    const int N = in_sizes[0] / 128;
    const int E = in_sizes[14];
    const int B = (N + 255) >> 8;

    // ---- workspace layout ----
    unsigned short* Wt = (unsigned short*)d_ws;               // 131072 bf16
    float* stats1 = (float*)((char*)d_ws + 262144);           // 256
    float* stats2 = stats1 + 256;                             // 256
    int* bCnt = (int*)(stats2 + 256);                         // 512
    int* bOff = bCnt + 512;                                   // 513
    int* bCur = bOff + 513;                                   // 512
    uintptr_t big = ((uintptr_t)(bCur + 512) + 255) & ~(uintptr_t)255;
    _Float16* Qh = (_Float16*)big;                            // N*128 f16
    _Float16* Kh = Qh + (size_t)N * 128;                      // N*128 f16
    unsigned char* V8u = (unsigned char*)(Kh + (size_t)N * 128);  // N*128 u8
    uintptr_t a2 = ((uintptr_t)(V8u + (size_t)N * 128) + 255) & ~(uintptr_t)255;
    unsigned short* attnb = (unsigned short*)a2;              // N*128 bf16
    unsigned short* xb = attnb + (size_t)N * 128;             // N*128 bf16
    int* row_ptr = (int*)(xb + (size_t)N * 128);              // N+1
    // overlays (lifetimes disjoint):
    unsigned* coarse = (unsigned*)attnb;   // CSR temp; attnb born at edge_attn
    int* esrc = (int*)xb;                  // CSR out, read by edge_attn; xb born at Wo-GEMM
    unsigned short* hidden = (unsigned short*)Qh;  // N*256; Qh/Kh dead after edge_attn
    unsigned short* yb = attnb;            // FFN2 bf16 out; attnb dead after Wo-GEMM

    unsigned short* Wf1T = Wt + 65536;
    unsigned short* Wf2T = Wt + 98304;

    float* out = (float*)d_out;
    const dim3 b256(256);
    const int gm = (N + 127) / 128;

    hipMemsetAsync(stats1, 0, 4096, stream);

    // ---- weight prep ----
    prep_all_k<<<dim3(512), b256, 0, stream>>>(Wq, Wk, Wv, Wo, Wf1, Wf2, Wt);

    // ---- CSR build ----
    bucket_cnt_k<<<dim3(256), b256, 0, stream>>>(dstv, E, bCnt);
    bucket_scan_k<<<dim3(1), dim3(512), 0, stream>>>(bCnt, B, bOff, bCur);
    coarse_k<<<dim3((E + CCH - 1) / CCH), dim3(512), 0, stream>>>(src, dstv, E, bCur, coarse);
    fine_k<<<dim3(B), b256, 0, stream>>>(coarse, bOff, B, N, row_ptr, esrc);

    // ---- fused QKV (f16 Q/K, biased-u8 V) ----
    qkv_k<<<dim3(gm), b256, 0, stream>>>(h, Wt, Qh, Kh, V8u, N);

    // ---- sparse attention -> attnb bf16 ----
    edge_attn_k<<<dim3((N + 3) / 4), b256, 0, stream>>>(Qh, Kh, V8u, row_ptr, esrc, attnb, N);

    // ---- x = h + attn @ Wo + bo (bf16 out) ; BN1 raw moments ----
    mm_k<1, 1, 1, 1><<<dim3(gm, 1), b256, 0, stream>>>(
        attnb, Wt + 49152, bo, h, xb, N, 128, 128, 0, nullptr, nullptr, stats1);
    bn_finalize_k<<<dim3(1), dim3(128), 0, stream>>>(stats1, g1, b1, N);

    // ---- FFN1: bf16 x + BN1 affine on read -> hidden bf16, relu ----
    mm_k<3, 1, 0, 0><<<dim3(gm, 2), b256, 0, stream>>>(
        xb, Wf1T, bf1, nullptr, hidden, N, 128, 256, 1, stats1, nullptr, nullptr);

    // ---- FFN2: resid = BN1(x) bf16-affine; BN2 raw moments -> yb bf16 ----
    mm_k<1, 1, 3, 1><<<dim3(gm, 1), b256, 0, stream>>>(
        hidden, Wf2T, bf2, xb, yb, N, 256, 128, 0, nullptr, stats1, stats2);
    bn_finalize_k<<<dim3(1), dim3(128), 0, stream>>>(stats2, g2, b2, N);

    // ---- BN2 apply: yb bf16 -> out fp32 ----
    bn_apply_b_k<<<dim3(1024), b256, 0, stream>>>(yb, stats2, N * 16, out);
}

// Round 7
// 541.350 us; speedup vs baseline: 2.3502x; 1.0052x over previous
//
#include <hip/hip_runtime.h>

#define EPS 1e-5f
#define VSCALE 20.0f

typedef __attribute__((ext_vector_type(8))) short sh8;
typedef __attribute__((ext_vector_type(4))) float f4;
typedef __attribute__((ext_vector_type(2))) _Float16 h2f;

static __device__ __forceinline__ unsigned short f2b(float f) {
    union { float f; unsigned u; } v; v.f = f;
    unsigned r = v.u + 0x7FFF + ((v.u >> 16) & 1);  // RNE
    return (unsigned short)(r >> 16);
}
static __device__ __forceinline__ float b2f(unsigned short b) {
    union { unsigned u; float f; } v; v.u = ((unsigned)b) << 16; return v.f;
}
static __device__ __forceinline__ unsigned pk2(float a, float b) {
    return (unsigned)f2b(a) | ((unsigned)f2b(b) << 16);
}
static __device__ __forceinline__ h2f u2h(unsigned u) {
    union { unsigned u; h2f h; } c; c.u = u; return c.h;
}
static __device__ __forceinline__ float dot2h(h2f a, h2f b, float c) {
#if __has_builtin(__builtin_amdgcn_fdot2)
    return __builtin_amdgcn_fdot2(a, b, c, false);
#else
    return (float)a.x * (float)b.x + (float)a.y * (float)b.y + c;
#endif
}

// ===================== weight prep (all 6, one launch) =====================
__global__ __launch_bounds__(256) void prep_all_k(
    const float* __restrict__ Wq, const float* __restrict__ Wk,
    const float* __restrict__ Wv, const float* __restrict__ Wo,
    const float* __restrict__ Wf1, const float* __restrict__ Wf2,
    unsigned short* __restrict__ Wt)
{
    int i = blockIdx.x * 256 + threadIdx.x;      // 0..131071
    if (i < 65536) {
        int s = i >> 14;
        const float* W = (s == 0) ? Wq : (s == 1) ? Wk : (s == 2) ? Wv : Wo;
        int l = i & 16383, k = l >> 7, n = l & 127;
        Wt[(i & ~16383) + n * 128 + k] = f2b(W[l]);
    } else if (i < 98304) {
        int l = i - 65536, k = l >> 8, n = l & 255;
        Wt[65536 + n * 128 + k] = f2b(Wf1[l]);
    } else {
        int l = i - 98304, k = l >> 7, n = l & 127;
        Wt[98304 + n * 256 + k] = f2b(Wf2[l]);
    }
}

// ===================== fused QKV GEMM ======================================
// Outputs: Qh f16 [N][128], Kh f16 [N][128], V8u uint8 biased (v*20+128)
__global__ __launch_bounds__(256) void qkv_k(
    const float* __restrict__ h, const unsigned short* __restrict__ Wt,
    _Float16* __restrict__ Qh, _Float16* __restrict__ Kh,
    unsigned char* __restrict__ V8u, int M)
{
    __shared__ __align__(16) unsigned short As[128 * 136];
    __shared__ __align__(16) unsigned short Ws[128 * 72];
    const int tid = threadIdx.x;
    const int wave = tid >> 6, lane = tid & 63;
    const int q = lane >> 4, lm = lane & 15;
    const int rowBase = blockIdx.x * 128;
    const int r0 = (wave & 1) * 64, c0 = (wave >> 1) * 64;

#pragma unroll
    for (int j = 0; j < 16; ++j) {
        int idx = tid + j * 256;
        int row = idx >> 5, kk = (idx & 31) * 4;
        int grow = rowBase + row;
        float4 v = make_float4(0.f, 0.f, 0.f, 0.f);
        if (grow < M) v = *(const float4*)&h[(size_t)grow * 128 + kk];
        ushort4 b;
        b.x = f2b(v.x); b.y = f2b(v.y); b.z = f2b(v.z); b.w = f2b(v.w);
        *(ushort4*)&As[row * 136 + kk] = b;
    }

    for (int w = 0; w < 3; ++w) {
        f4 acc[4][4];
#pragma unroll
        for (int mi = 0; mi < 4; ++mi)
#pragma unroll
            for (int ni = 0; ni < 4; ++ni) {
                f4 z = {0.f, 0.f, 0.f, 0.f};
                acc[mi][ni] = z;
            }
        for (int kc = 0; kc < 2; ++kc) {
#pragma unroll
            for (int j = 0; j < 4; ++j) {
                int idx = tid + j * 256;
                int n = idx >> 3, kk = (idx & 7) * 8;
                uint4 v = *(const uint4*)&Wt[(size_t)w * 16384 + (size_t)n * 128 + kc * 64 + kk];
                *(uint4*)&Ws[n * 72 + kk] = v;
            }
            __syncthreads();
#pragma unroll
            for (int k2 = 0; k2 < 2; ++k2) {
                sh8 af[4], bfr[4];
#pragma unroll
                for (int t = 0; t < 4; ++t) {
                    af[t]  = *(const sh8*)&As[(r0 + t * 16 + lm) * 136 + kc * 64 + k2 * 32 + q * 8];
                    bfr[t] = *(const sh8*)&Ws[(c0 + t * 16 + lm) * 72 + k2 * 32 + q * 8];
                }
#pragma unroll
                for (int mi = 0; mi < 4; ++mi)
#pragma unroll
                    for (int ni = 0; ni < 4; ++ni)
                        acc[mi][ni] = __builtin_amdgcn_mfma_f32_16x16x32_bf16(
                            af[mi], bfr[ni], acc[mi][ni], 0, 0, 0);
            }
            __syncthreads();
        }
#pragma unroll
        for (int mi = 0; mi < 4; ++mi)
#pragma unroll
            for (int ni = 0; ni < 4; ++ni) {
                const int col = c0 + ni * 16 + lm;
#pragma unroll
                for (int r = 0; r < 4; ++r) {
                    int grow = rowBase + r0 + mi * 16 + q * 4 + r;
                    if (grow >= M) continue;
                    const float v = acc[mi][ni][r];
                    if (w == 0) Qh[(size_t)grow * 128 + col] = (_Float16)v;
                    else if (w == 1) Kh[(size_t)grow * 128 + col] = (_Float16)v;
                    else {
                        float t = rintf(v * VSCALE);
                        t = fminf(fmaxf(t, -127.f), 127.f);
                        V8u[(size_t)grow * 128 + col] = (unsigned char)(int)(t + 128.f);
                    }
                }
            }
    }
}

// ===================== MFMA GEMM ===========================================
// AMODE: 1 bf16 A, 3 bf16 A + BN affine (finalized per-block from raw rstats)
// OMODE: 0 fp32 out, 1 bf16 out
// RESMODE: 0 none, 1 fp32 resid, 3 bf16 resid + BN affine (same rstats)
// STATS: accumulate per-column raw sum/sumsq of output into ostats
template<int AMODE, int OMODE, int RESMODE, int STATS>
__global__ __launch_bounds__(256) void mm_k(
    const void* __restrict__ Ap, const unsigned short* __restrict__ Wt,
    const float* __restrict__ bias, const void* __restrict__ resid,
    void* __restrict__ Cp, int M, int Kdim, int ldc, int relu,
    const float* __restrict__ rstats, const float* __restrict__ gma,
    const float* __restrict__ bta, float invN, float* __restrict__ ostats)
{
    __shared__ __align__(16) unsigned short As[128 * 72];
    __shared__ __align__(16) unsigned short Ws[128 * 72];
    __shared__ float aff[256];
    const int tid = threadIdx.x;
    const int wave = tid >> 6, lane = tid & 63;
    const int q = lane >> 4, lm = lane & 15;
    const int rowBase = blockIdx.x * 128;
    const int colBase = blockIdx.y * 128;
    const unsigned short* Wblk = Wt + (size_t)colBase * Kdim;
    const int r0 = (wave & 1) * 64, c0 = (wave >> 1) * 64;

    if (AMODE == 3 || RESMODE == 3) {
        if (tid < 128) {
            const float mu = rstats[tid] * invN;
            const float var = rstats[128 + tid] * invN - mu * mu;
            const float isg = rsqrtf(var + EPS) * gma[tid];
            aff[tid] = isg;
            aff[128 + tid] = bta[tid] - mu * isg;
        }
        __syncthreads();
    }

    f4 acc[4][4];
#pragma unroll
    for (int mi = 0; mi < 4; ++mi)
#pragma unroll
        for (int ni = 0; ni < 4; ++ni) {
            f4 z = {0.f, 0.f, 0.f, 0.f};
            acc[mi][ni] = z;
        }

    for (int kc = 0; kc < Kdim; kc += 64) {
        const unsigned short* A = (const unsigned short*)Ap;
#pragma unroll
        for (int j = 0; j < 4; ++j) {
            int idx = tid + j * 256;
            int row = idx >> 3, kk = (idx & 7) * 8;
            int grow = rowBase + row;
            uint4 v = make_uint4(0u, 0u, 0u, 0u);
            if (grow < M) v = *(const uint4*)&A[(size_t)grow * Kdim + kc + kk];
            if (AMODE == 3) {
                const int f = kc + kk;
                const float4 sc0 = *(const float4*)&aff[f];
                const float4 sc1 = *(const float4*)&aff[f + 4];
                const float4 sh0 = *(const float4*)&aff[128 + f];
                const float4 sh1 = *(const float4*)&aff[128 + f + 4];
                uint4 o;
                o.x = pk2(b2f((unsigned short)(v.x & 0xffff)) * sc0.x + sh0.x,
                          b2f((unsigned short)(v.x >> 16)) * sc0.y + sh0.y);
                o.y = pk2(b2f((unsigned short)(v.y & 0xffff)) * sc0.z + sh0.z,
                          b2f((unsigned short)(v.y >> 16)) * sc0.w + sh0.w);
                o.z = pk2(b2f((unsigned short)(v.z & 0xffff)) * sc1.x + sh1.x,
                          b2f((unsigned short)(v.z >> 16)) * sc1.y + sh1.y);
                o.w = pk2(b2f((unsigned short)(v.w & 0xffff)) * sc1.z + sh1.z,
                          b2f((unsigned short)(v.w >> 16)) * sc1.w + sh1.w);
                v = o;
            }
            *(uint4*)&As[row * 72 + kk] = v;
        }
#pragma unroll
        for (int j = 0; j < 4; ++j) {
            int idx = tid + j * 256;
            int n = idx >> 3, kk = (idx & 7) * 8;
            uint4 v = *(const uint4*)&Wblk[(size_t)n * Kdim + kc + kk];
            *(uint4*)&Ws[n * 72 + kk] = v;
        }
        __syncthreads();
#pragma unroll
        for (int k2 = 0; k2 < 2; ++k2) {
            sh8 af[4], bfr[4];
#pragma unroll
            for (int t = 0; t < 4; ++t) {
                af[t]  = *(const sh8*)&As[(r0 + t * 16 + lm) * 72 + k2 * 32 + q * 8];
                bfr[t] = *(const sh8*)&Ws[(c0 + t * 16 + lm) * 72 + k2 * 32 + q * 8];
            }
#pragma unroll
            for (int mi = 0; mi < 4; ++mi)
#pragma unroll
                for (int ni = 0; ni < 4; ++ni)
                    acc[mi][ni] = __builtin_amdgcn_mfma_f32_16x16x32_bf16(
                        af[mi], bfr[ni], acc[mi][ni], 0, 0, 0);
        }
        __syncthreads();
    }

#pragma unroll
    for (int ni = 0; ni < 4; ++ni) {
        const int gcol = colBase + c0 + ni * 16 + lm;
        const float bv = bias ? bias[gcol] : 0.f;
        float s = 0.f, ss = 0.f;
#pragma unroll
        for (int mi = 0; mi < 4; ++mi) {
#pragma unroll
            for (int r = 0; r < 4; ++r) {
                int grow = rowBase + r0 + mi * 16 + q * 4 + r;
                if (grow >= M) continue;
                float val = acc[mi][ni][r] + bv;
                if (RESMODE == 1)
                    val += ((const float*)resid)[(size_t)grow * ldc + gcol];
                if (RESMODE == 3)
                    val += b2f(((const unsigned short*)resid)[(size_t)grow * ldc + gcol])
                           * aff[gcol] + aff[128 + gcol];
                if (relu) val = fmaxf(val, 0.f);
                if (STATS) { s += val; ss += val * val; }
                if (OMODE == 0) ((float*)Cp)[(size_t)grow * ldc + gcol] = val;
                else ((unsigned short*)Cp)[(size_t)grow * ldc + gcol] = f2b(val);
            }
        }
        if (STATS) {
            s += __shfl_xor(s, 16); s += __shfl_xor(s, 32);
            ss += __shfl_xor(ss, 16); ss += __shfl_xor(ss, 32);
            if (q == 0) {
                atomicAdd(&ostats[gcol], s);
                atomicAdd(&ostats[128 + gcol], ss);
            }
        }
    }
}

// ============== CSR build: two-level LDS counting sort =====================
__global__ __launch_bounds__(256) void bucket_cnt_k(const int* __restrict__ dst,
                                                    int E, int* __restrict__ bCnt)
{
    __shared__ int c[512];
    const int t = threadIdx.x;
    c[t] = 0; c[t + 256] = 0;
    __syncthreads();
    for (int i = blockIdx.x * 256 + t; i < E; i += gridDim.x * 256)
        atomicAdd(&c[dst[i] >> 8], 1);
    __syncthreads();
    if (c[t]) atomicAdd(&bCnt[t], c[t]);
    if (c[t + 256]) atomicAdd(&bCnt[t + 256], c[t + 256]);
}

__global__ __launch_bounds__(512) void bucket_scan_k(const int* __restrict__ bCnt,
                                                     int B, int* __restrict__ bOff,
                                                     int* __restrict__ bCur)
{
    __shared__ int ts[512];
    const int t = threadIdx.x;
    const int v = (t < B) ? bCnt[t] : 0;
    ts[t] = v;
    __syncthreads();
    for (int o = 1; o < 512; o <<= 1) {
        int u = (t >= o) ? ts[t - o] : 0;
        __syncthreads();
        ts[t] += u;
        __syncthreads();
    }
    const int ex = ts[t] - v;
    if (t < B) { bOff[t] = ex; bCur[t] = ex; }
    if (t == B - 1) bOff[B] = ex + v;
}

#define CCH 8192
__global__ __launch_bounds__(512) void coarse_k(const int* __restrict__ src,
                                                const int* __restrict__ dst, int E,
                                                int* __restrict__ bCur,
                                                unsigned* __restrict__ coarse)
{
    __shared__ int cnt[512], off[512], gbase[512], rc[512];
    __shared__ unsigned pk[CCH];
    __shared__ int ga[CCH];
    const int t = threadIdx.x;
    const int e0 = blockIdx.x * CCH;
    const int n = min(CCH, E - e0);
    cnt[t] = 0;
    __syncthreads();
    for (int i = t; i < n; i += 512) atomicAdd(&cnt[dst[e0 + i] >> 8], 1);
    __syncthreads();
    const int v = cnt[t];
    off[t] = v;
    __syncthreads();
    for (int o = 1; o < 512; o <<= 1) {
        int u = (t >= o) ? off[t - o] : 0;
        __syncthreads();
        off[t] += u;
        __syncthreads();
    }
    const int ex = off[t] - v;
    off[t] = ex;
    if (v > 0) gbase[t] = atomicAdd(&bCur[t], v);
    rc[t] = 0;
    __syncthreads();
    for (int i = t; i < n; i += 512) {
        const int d = dst[e0 + i], s = src[e0 + i];
        const int b = d >> 8;
        const int j = atomicAdd(&rc[b], 1);
        const int slot = off[b] + j;
        pk[slot] = ((unsigned)(d & 255) << 17) | (unsigned)s;
        ga[slot] = gbase[b] + j;
    }
    __syncthreads();
    for (int i = t; i < n; i += 512) coarse[ga[i]] = pk[i];
}

__global__ __launch_bounds__(256) void fine_k(const unsigned* __restrict__ coarse,
                                              const int* __restrict__ bOff, int B,
                                              int Nn, int* __restrict__ row_ptr,
                                              int* __restrict__ esrc)
{
    __shared__ int cnt[256], off[256], rc[256];
    const int t = threadIdx.x;
    const int b = blockIdx.x;
    const int base = b << 8;
    const int e0 = bOff[b], e1 = bOff[b + 1];
    cnt[t] = 0;
    __syncthreads();
    for (int i = e0 + t; i < e1; i += 256)
        atomicAdd(&cnt[(coarse[i] >> 17) & 255], 1);
    __syncthreads();
    const int v = cnt[t];
    off[t] = v;
    __syncthreads();
    for (int o = 1; o < 256; o <<= 1) {
        int u = (t >= o) ? off[t - o] : 0;
        __syncthreads();
        off[t] += u;
        __syncthreads();
    }
    const int ex = off[t] - v;
    off[t] = ex;
    rc[t] = 0;
    if (base + t < Nn) row_ptr[base + t] = e0 + ex;
    if (b == B - 1 && t == 0) row_ptr[Nn] = e1;
    __syncthreads();
    for (int i = e0 + t; i < e1; i += 256) {
        const unsigned p = coarse[i];
        const int l = (p >> 17) & 255;
        const int j = atomicAdd(&rc[l], 1);
        esrc[e0 + off[l] + j] = (int)(p & 0x1FFFFu);
    }
}

// ============================ edge attention ===============================
// Wave per node. lane = (p = l>>4 edge-slot 0..3, g = l&15 dim-group).
// Lane owns dims 8g..8g+7 of edge j+p. Head = g>>1; score reduce = 1 shfl_xor.
// K f16 (dwordx4 + 4x fdot2), V biased uint8 (true = u-128, scaled VSCALE).
// Next iteration's s/K/V prefetched into registers (3 loads in flight).
__global__ __launch_bounds__(256) void edge_attn_k(
    const _Float16* __restrict__ Qh, const _Float16* __restrict__ Kh,
    const unsigned char* __restrict__ V8u, const int* __restrict__ row_ptr,
    const int* __restrict__ esrc, unsigned short* __restrict__ attnb, int Nn)
{
    const int wave = threadIdx.x >> 6, lane = threadIdx.x & 63;
    const int node = blockIdx.x * 4 + wave;
    if (node >= Nn) return;
    const int g = lane & 15, p = lane >> 4;
    const uint4 qv = *(const uint4*)&Qh[(size_t)node * 128 + g * 8];
    const h2f q0 = u2h(qv.x), q1 = u2h(qv.y), q2 = u2h(qv.z), q3 = u2h(qv.w);
    const int e0 = row_ptr[node], e1 = row_ptr[node + 1];
    const int cnt = e1 - e0;
    float a0 = 0.f, a1 = 0.f, a2 = 0.f, a3 = 0.f;
    float a4 = 0.f, a5 = 0.f, a6 = 0.f, a7 = 0.f, z = 0.f;
    for (int base = 0; base < cnt; base += 64) {
        const int nb = min(cnt - base, 64);
        const int myS = (lane < nb) ? esrc[e0 + base + lane] : 0;
        int s = __shfl(myS, p);
        uint4 kv = *(const uint4*)&Kh[(size_t)s * 128 + g * 8];
        uint2 vv = *(const uint2*)&V8u[(size_t)s * 128 + g * 8];
        for (int j = 0; j < nb; j += 4) {
            const uint4 kc = kv;
            const uint2 vc = vv;
            const int ei = j + p;
            const int jn = j + 4;
            if (jn < nb) {                       // wave-uniform branch
                const int sn = __shfl(myS, jn + p);
                kv = *(const uint4*)&Kh[(size_t)sn * 128 + g * 8];
                vv = *(const uint2*)&V8u[(size_t)sn * 128 + g * 8];
            }
            float sp = dot2h(u2h(kc.w), q3, dot2h(u2h(kc.z), q2,
                       dot2h(u2h(kc.y), q1, dot2h(u2h(kc.x), q0, 0.f))));
            sp += __shfl_xor(sp, 1);             // 16-dim head dot
            float sc = __expf(fminf(fmaxf(sp * 0.25f, -5.f), 5.f));
            sc = (ei < nb) ? sc : 0.f;
            a0 += sc * (float)(vc.x & 0xffu);
            a1 += sc * (float)((vc.x >> 8) & 0xffu);
            a2 += sc * (float)((vc.x >> 16) & 0xffu);
            a3 += sc * (float)(vc.x >> 24);
            a4 += sc * (float)(vc.y & 0xffu);
            a5 += sc * (float)((vc.y >> 8) & 0xffu);
            a6 += sc * (float)((vc.y >> 16) & 0xffu);
            a7 += sc * (float)(vc.y >> 24);
            z += sc;
        }
    }
    // combine the 4 edge slots
    a0 += __shfl_xor(a0, 16); a0 += __shfl_xor(a0, 32);
    a1 += __shfl_xor(a1, 16); a1 += __shfl_xor(a1, 32);
    a2 += __shfl_xor(a2, 16); a2 += __shfl_xor(a2, 32);
    a3 += __shfl_xor(a3, 16); a3 += __shfl_xor(a3, 32);
    a4 += __shfl_xor(a4, 16); a4 += __shfl_xor(a4, 32);
    a5 += __shfl_xor(a5, 16); a5 += __shfl_xor(a5, 32);
    a6 += __shfl_xor(a6, 16); a6 += __shfl_xor(a6, 32);
    a7 += __shfl_xor(a7, 16); a7 += __shfl_xor(a7, 32);
    z  += __shfl_xor(z, 16);  z  += __shfl_xor(z, 32);
    const float inv = 1.f / (z * VSCALE);
    const float c = 128.f * z;
    if (p == 0) {
        uint4 o;
        o.x = pk2((a0 - c) * inv, (a1 - c) * inv);
        o.y = pk2((a2 - c) * inv, (a3 - c) * inv);
        o.z = pk2((a4 - c) * inv, (a5 - c) * inv);
        o.w = pk2((a6 - c) * inv, (a7 - c) * inv);
        *(uint4*)&attnb[(size_t)node * 128 + g * 8] = o;
    }
}

// ============================ BN apply (folds finalize) ====================
// reads bf16 X + raw stats2, writes fp32 out; 8 elems/thread
__global__ __launch_bounds__(256) void bn_apply_b_k(const unsigned short* __restrict__ X,
                                                    const float* __restrict__ rstats,
                                                    const float* __restrict__ gma,
                                                    const float* __restrict__ bta,
                                                    float invN, int total8,
                                                    float* __restrict__ out)
{
    __shared__ float aff[256];
    if (threadIdx.x < 128) {
        const int c = threadIdx.x;
        const float mu = rstats[c] * invN;
        const float var = rstats[128 + c] * invN - mu * mu;
        const float isg = rsqrtf(var + EPS) * gma[c];
        aff[c] = isg;
        aff[128 + c] = bta[c] - mu * isg;
    }
    __syncthreads();
    for (int i = blockIdx.x * blockDim.x + threadIdx.x; i < total8;
         i += gridDim.x * blockDim.x) {
        const int c8 = (i & 15) * 8;
        const float4 sc0 = *(const float4*)&aff[c8];
        const float4 sc1 = *(const float4*)&aff[c8 + 4];
        const float4 sh0 = *(const float4*)&aff[128 + c8];
        const float4 sh1 = *(const float4*)&aff[128 + c8 + 4];
        const uint4 v = ((const uint4*)X)[i];
        float4 o0, o1;
        o0.x = b2f((unsigned short)(v.x & 0xffff)) * sc0.x + sh0.x;
        o0.y = b2f((unsigned short)(v.x >> 16))    * sc0.y + sh0.y;
        o0.z = b2f((unsigned short)(v.y & 0xffff)) * sc0.z + sh0.z;
        o0.w = b2f((unsigned short)(v.y >> 16))    * sc0.w + sh0.w;
        o1.x = b2f((unsigned short)(v.z & 0xffff)) * sc1.x + sh1.x;
        o1.y = b2f((unsigned short)(v.z >> 16))    * sc1.y + sh1.y;
        o1.z = b2f((unsigned short)(v.w & 0xffff)) * sc1.z + sh1.z;
        o1.w = b2f((unsigned short)(v.w >> 16))    * sc1.w + sh1.w;
        ((float4*)out)[i * 2]     = o0;
        ((float4*)out)[i * 2 + 1] = o1;
    }
}

// ============================ launch =======================================
extern "C" void kernel_launch(void* const* d_in, const int* in_sizes, int n_in,
                              void* d_out, int out_size, void* d_ws, size_t ws_size,
                              hipStream_t stream)
{
    const float* h   = (const float*)d_in[0];
    const float* Wq  = (const float*)d_in[1];
    const float* Wk  = (const float*)d_in[2];
    const float* Wv  = (const float*)d_in[3];
    const float* Wo  = (const float*)d_in[4];
    const float* bo  = (const float*)d_in[5];
    const float* g1  = (const float*)d_in[6];
    const float* b1  = (const float*)d_in[7];
    const float* Wf1 = (const float*)d_in[8];
    const float* bf1 = (const float*)d_in[9];
    const float* Wf2 = (const float*)d_in[10];
    const float* bf2 = (const float*)d_in[11];
    const float* g2  = (const float*)d_in[12];
    const float* b2  = (const float*)d_in[13];
    const int*   src = (const int*)d_in[14];
    const int*   dstv= (const int*)d_in[15];
    const int N = in_sizes[0] / 128;
    const int E = in_sizes[14];
    const int B = (N + 255) >> 8;
    const float invN = 1.f / (float)N;

    // ---- workspace layout ----
    unsigned short* Wt = (unsigned short*)d_ws;               // 131072 bf16
    float* stats1 = (float*)((char*)d_ws + 262144);           // 256
    float* stats2 = stats1 + 256;                             // 256
    int* bCnt = (int*)(stats2 + 256);                         // 512
    int* bOff = bCnt + 512;                                   // 513
    int* bCur = bOff + 513;                                   // 512
    uintptr_t big = ((uintptr_t)(bCur + 512) + 255) & ~(uintptr_t)255;
    _Float16* Qh = (_Float16*)big;                            // N*128 f16
    _Float16* Kh = Qh + (size_t)N * 128;                      // N*128 f16
    unsigned char* V8u = (unsigned char*)(Kh + (size_t)N * 128);  // N*128 u8
    uintptr_t a2 = ((uintptr_t)(V8u + (size_t)N * 128) + 255) & ~(uintptr_t)255;
    unsigned short* attnb = (unsigned short*)a2;              // N*128 bf16
    unsigned short* xb = attnb + (size_t)N * 128;             // N*128 bf16
    int* row_ptr = (int*)(xb + (size_t)N * 128);              // N+1
    // overlays (lifetimes disjoint):
    unsigned* coarse = (unsigned*)attnb;   // CSR temp; attnb born at edge_attn
    int* esrc = (int*)xb;                  // CSR out; xb born at Wo-GEMM
    unsigned short* hidden = (unsigned short*)Qh;  // N*256; Qh/Kh dead after edge_attn
    unsigned short* yb = attnb;            // FFN2 bf16 out; attnb dead after Wo-GEMM

    unsigned short* Wf1T = Wt + 65536;
    unsigned short* Wf2T = Wt + 98304;

    float* out = (float*)d_out;
    const dim3 b256(256);
    const int gm = (N + 127) / 128;

    hipMemsetAsync(stats1, 0, 4096, stream);

    // ---- weight prep ----
    prep_all_k<<<dim3(512), b256, 0, stream>>>(Wq, Wk, Wv, Wo, Wf1, Wf2, Wt);

    // ---- CSR build ----
    bucket_cnt_k<<<dim3(256), b256, 0, stream>>>(dstv, E, bCnt);
    bucket_scan_k<<<dim3(1), dim3(512), 0, stream>>>(bCnt, B, bOff, bCur);
    coarse_k<<<dim3((E + CCH - 1) / CCH), dim3(512), 0, stream>>>(src, dstv, E, bCur, coarse);
    fine_k<<<dim3(B), b256, 0, stream>>>(coarse, bOff, B, N, row_ptr, esrc);

    // ---- fused QKV (f16 Q/K, biased-u8 V) ----
    qkv_k<<<dim3(gm), b256, 0, stream>>>(h, Wt, Qh, Kh, V8u, N);

    // ---- sparse attention -> attnb bf16 ----
    edge_attn_k<<<dim3((N + 3) / 4), b256, 0, stream>>>(Qh, Kh, V8u, row_ptr, esrc, attnb, N);

    // ---- x = h + attn @ Wo + bo (bf16 out) ; BN1 raw moments ----
    mm_k<1, 1, 1, 1><<<dim3(gm, 1), b256, 0, stream>>>(
        attnb, Wt + 49152, bo, h, xb, N, 128, 128, 0,
        nullptr, nullptr, nullptr, invN, stats1);

    // ---- FFN1: bf16 x + BN1 affine (finalized per-block) -> hidden, relu ----
    mm_k<3, 1, 0, 0><<<dim3(gm, 2), b256, 0, stream>>>(
        xb, Wf1T, bf1, nullptr, hidden, N, 128, 256, 1,
        stats1, g1, b1, invN, nullptr);

    // ---- FFN2: resid = BN1(x); BN2 raw moments -> yb bf16 ----
    mm_k<1, 1, 3, 1><<<dim3(gm, 1), b256, 0, stream>>>(
        hidden, Wf2T, bf2, xb, yb, N, 256, 128, 0,
        stats1, g1, b1, invN, stats2);

    // ---- BN2 apply (finalize folded): yb bf16 -> out fp32 ----
    bn_apply_b_k<<<dim3(1024), b256, 0, stream>>>(yb, stats2, g2, b2, invN, N * 16, out);
}